// Round 13
// baseline (114.119 us; speedup 1.0000x reference)
//
#include <hip/hip_runtime.h>
#include <hip/hip_bf16.h>
#include <cstdint>

// Problem constants
#define B_  128
#define F_  512
#define T_  60
#define C_  15
#define H1_ 128
#define H2_ 64

typedef short short8_t __attribute__((ext_vector_type(8)));   // 8 bf16 (4 VGPR)
typedef float f32x4    __attribute__((ext_vector_type(4)));   // MFMA acc

static __device__ __forceinline__ unsigned short f2bf(float f) {
    union { float f; uint32_t u; } v; v.f = f;
    uint32_t r = v.u + 0x7FFF + ((v.u >> 16) & 1);   // RNE
    return (unsigned short)(r >> 16);
}

// async 16B global -> LDS DMA (dest = wave-uniform base + lane*16)
static __device__ __forceinline__ void async_cp16(const unsigned short* g, unsigned short* l) {
    __builtin_amdgcn_global_load_lds(
        (const __attribute__((address_space(1))) unsigned int*)g,
        (__attribute__((address_space(3))) unsigned int*)l, 16, 0, 0);
}

// ---------------------------------------------------------------------------
// Camera-sort: ord[rank] = b, stable sort of b by cam[b]. 1 block, 128 thr.
// ---------------------------------------------------------------------------
__global__ __launch_bounds__(128) void make_order(const int* __restrict__ cam,
                                                  int* __restrict__ ord) {
    __shared__ int cs[B_];
    const int b = threadIdx.x;
    cs[b] = cam[b];
    __syncthreads();
    const int cb = cs[b];
    int rank = 0;
    #pragma unroll 16
    for (int j = 0; j < B_; ++j) {
        int cj = cs[j];
        rank += (cj < cb || (cj == cb && j < b)) ? 1 : 0;
    }
    ord[rank] = b;
}

// ---------------------------------------------------------------------------
// Repack x (B,F,T) f32 -> xTs (B, 8 kc-chunks, swizzled 64x64 LDS image) bf16.
// unit (kc, row t, cc): holds k = kc*64 + (cc ^ (t&7))*8 .. +8
// ---------------------------------------------------------------------------
__global__ __launch_bounds__(256) void repack_x(const float* __restrict__ x,
                                                unsigned short* __restrict__ xTs) {
    __shared__ float xs[128][61];
    const int f0 = blockIdx.x * 128, b = blockIdx.y, tid = threadIdx.x;
    #pragma unroll
    for (int it = 0; it < 32; ++it) {
        int idx = tid + it * 256;          // 128*64
        int fl = idx >> 6, t = idx & 63;
        if (t < T_) xs[fl][t] = x[((size_t)b * F_ + f0 + fl) * T_ + t];
    }
    __syncthreads();
    #pragma unroll
    for (int it = 0; it < 8; ++it) {
        int idx = tid + it * 256;          // 64*32
        int t = idx >> 5, f4 = (idx & 31) * 4;
        ushort4 o;
        o.x = (t < T_) ? f2bf(xs[f4 + 0][t]) : 0;
        o.y = (t < T_) ? f2bf(xs[f4 + 1][t]) : 0;
        o.z = (t < T_) ? f2bf(xs[f4 + 2][t]) : 0;
        o.w = (t < T_) ? f2bf(xs[f4 + 3][t]) : 0;
        const int f = f0 + f4;
        const int kc = f >> 6, within = f & 63;
        const int cc = (within >> 3) ^ (t & 7), half = (within >> 2) & 1;
        *(ushort4*)(xTs + (size_t)b * 32768 + kc * 4096 + t * 64 + cc * 8 + half * 4) = o;
    }
}

// ---------------------------------------------------------------------------
// Repack W1 (C,F,H1,3,4) f32 -> W1s[(c*12+pq)][kc][swizzled 128x64 image] bf16
//   slice = 65536 ush; kc chunk = 8192 ush; unit k = kc*64 + (cc^(i&7))*8..+8
// ---------------------------------------------------------------------------
__global__ __launch_bounds__(256) void repack_w1(const float* __restrict__ W1,
                                                 unsigned short* __restrict__ W1s) {
    __shared__ float ls[32][384];
    const int f0 = blockIdx.x * 32, i0 = blockIdx.y * 32, c = blockIdx.z;
    const int tid = threadIdx.x;
    #pragma unroll
    for (int it = 0; it < 12; ++it) {
        int idx = tid + it * 256;              // 3072 float4
        int fl = idx / 96, r = idx - fl * 96;
        float4 v = *(const float4*)(W1 + ((size_t)(c * F_ + f0 + fl)) * (H1_ * 12)
                                       + (size_t)i0 * 12 + r * 4);
        *(float4*)&ls[fl][r * 4] = v;
    }
    __syncthreads();
    const int i_l = tid >> 3, f_l = (tid & 7) * 4;
    const int i = i0 + i_l, f = f0 + f_l;
    const int kc = f >> 6, within = f & 63;
    const int cc = (within >> 3) ^ (i & 7), half = (within >> 2) & 1;
    #pragma unroll
    for (int pq = 0; pq < 12; ++pq) {
        ushort4 o;
        o.x = f2bf(ls[f_l + 0][i_l * 12 + pq]);
        o.y = f2bf(ls[f_l + 1][i_l * 12 + pq]);
        o.z = f2bf(ls[f_l + 2][i_l * 12 + pq]);
        o.w = f2bf(ls[f_l + 3][i_l * 12 + pq]);
        *(ushort4*)(W1s + (size_t)(c * 12 + pq) * 65536
                        + kc * 8192 + i * 64 + cc * 8 + half * 4) = o;
    }
}

// ---------------------------------------------------------------------------
// Repack W2 (C,H1,H2,3,4) f32 -> W2b[(c*12+rs)][o][i] bf16
// ---------------------------------------------------------------------------
__global__ __launch_bounds__(256) void repack_w2(const float* __restrict__ W2,
                                                 unsigned short* __restrict__ W2b) {
    __shared__ float ls[32][384];
    const int i0 = blockIdx.x * 32, o0 = blockIdx.y * 32, c = blockIdx.z;
    const int tid = threadIdx.x;
    #pragma unroll
    for (int it = 0; it < 12; ++it) {
        int idx = tid + it * 256;
        int il = idx / 96, r = idx - il * 96;
        float4 v = *(const float4*)(W2 + ((size_t)(c * H1_ + i0 + il)) * (H2_ * 12)
                                       + (size_t)o0 * 12 + r * 4);
        *(float4*)&ls[il][r * 4] = v;
    }
    __syncthreads();
    const int o_l = tid >> 3, i_l = (tid & 7) * 4;
    #pragma unroll
    for (int rs = 0; rs < 12; ++rs) {
        ushort4 o;
        o.x = f2bf(ls[i_l + 0][o_l * 12 + rs]);
        o.y = f2bf(ls[i_l + 1][o_l * 12 + rs]);
        o.z = f2bf(ls[i_l + 2][o_l * 12 + rs]);
        o.w = f2bf(ls[i_l + 3][o_l * 12 + rs]);
        *(ushort4*)(W2b + (((size_t)(c * 12 + rs)) * H2_ + o0 + o_l) * H1_ + i0 + i_l) = o;
    }
}

// ---------------------------------------------------------------------------
// Kernel A (phase 1): h1(64x128) = relu(xT * W1^T + b1) -> h1g (global bf16,
// [b*12+pq][t][i] linear, 8192 ush/tile). R10's staging loop + coalesced
// writeout (FIXED: 16 x 16B units per row, t = u>>4, i16 = u&15).
// ---------------------------------------------------------------------------
__global__ __launch_bounds__(256) void fused_p1(
    const unsigned short* __restrict__ xTs, const unsigned short* __restrict__ W1s,
    const int* __restrict__ cam, const int* __restrict__ ord,
    const float* __restrict__ b1, unsigned short* __restrict__ h1g)
{
    __shared__ __align__(16) unsigned short smem[24576];   // 48 KB

    const int idx = blockIdx.x;
    const int swz = (idx & 7) * 192 + (idx >> 3);   // bijective XCD swizzle
    const int bpos = swz / 12, pq = swz - bpos * 12;
    const int b = ord[bpos];

    const int tid = threadIdx.x;
    const int w = tid >> 6, l = tid & 63;
    const int l15 = l & 15, g = l >> 4;
    const int c = cam[b];

    const unsigned short* xchunk = xTs + (size_t)b * 32768;             // 8 x 4096
    const unsigned short* wchunk = W1s + (size_t)(c * 12 + pq) * 65536; // 8 x 8192

    #define STAGE1(kc, buf)                                                       \
        {                                                                         \
            _Pragma("unroll")                                                     \
            for (int k = 0; k < 2; ++k)                                           \
                async_cp16(xchunk + (kc) * 4096 + (w * 2 + k) * 512 + l * 8,      \
                           smem + (buf) * 12288 + (w * 2 + k) * 512 + l * 8);     \
            _Pragma("unroll")                                                     \
            for (int k = 0; k < 4; ++k)                                           \
                async_cp16(wchunk + (kc) * 8192 + (w * 4 + k) * 512 + l * 8,      \
                           smem + (buf) * 12288 + 4096 + (w * 4 + k) * 512 + l * 8); \
        }

    f32x4 acc1[4][2];
    #pragma unroll
    for (int mt = 0; mt < 4; ++mt) {
        acc1[mt][0] = (f32x4){0.f, 0.f, 0.f, 0.f};
        acc1[mt][1] = (f32x4){0.f, 0.f, 0.f, 0.f};
    }

    STAGE1(0, 0);
    STAGE1(1, 1);

    const int sxor = (l15 & 7);
    #pragma unroll
    for (int kc = 0; kc < 8; ++kc) {
        if (kc < 7) { asm volatile("s_waitcnt vmcnt(6)" ::: "memory"); }
        else        { asm volatile("s_waitcnt vmcnt(0)" ::: "memory"); }
        __builtin_amdgcn_s_barrier();
        asm volatile("" ::: "memory");

        const int base = (kc & 1) * 12288;
        #pragma unroll
        for (int kk2 = 0; kk2 < 2; ++kk2) {
            const int cc = (kk2 * 4 + g) ^ sxor;
            short8_t af[4], bf[2];
            #pragma unroll
            for (int mt = 0; mt < 4; ++mt)
                af[mt] = *(const short8_t*)(smem + base + (16 * mt + l15) * 64 + cc * 8);
            #pragma unroll
            for (int ni = 0; ni < 2; ++ni)
                bf[ni] = *(const short8_t*)(smem + base + 4096
                                            + (32 * w + 16 * ni + l15) * 64 + cc * 8);
            #pragma unroll
            for (int mt = 0; mt < 4; ++mt)
                #pragma unroll
                for (int ni = 0; ni < 2; ++ni)
                    acc1[mt][ni] = __builtin_amdgcn_mfma_f32_16x16x32_bf16(
                        af[mt], bf[ni], acc1[mt][ni], 0, 0, 0);
        }

        asm volatile("" ::: "memory");
        __builtin_amdgcn_s_barrier();
        if (kc < 6) STAGE1(kc + 2, kc & 1);
    }
    #undef STAGE1

    // bias + relu -> h1s [64][136] (bank-staggered), then coalesced writeout
    unsigned short* h1s = smem;
    #pragma unroll
    for (int ni = 0; ni < 2; ++ni) {
        const int i = 32 * w + 16 * ni + l15;
        const float b1v = b1[c * H1_ + i];
        #pragma unroll
        for (int mt = 0; mt < 4; ++mt)
            #pragma unroll
            for (int r = 0; r < 4; ++r) {
                float h = acc1[mt][ni][r] + b1v;
                h = h > 0.f ? h : 0.f;
                h1s[(16 * mt + 4 * g + r) * 136 + i] = f2bf(h);
            }
    }
    __syncthreads();

    // 64 rows x 128 ush = 1024 x 16B units; 16 units per row
    unsigned short* dst = h1g + (size_t)(b * 12 + pq) * 8192;
    #pragma unroll
    for (int it = 0; it < 4; ++it) {
        int u = tid + it * 256;            // 0..1023
        int t = u >> 4, i16 = u & 15;
        short8_t v = *(const short8_t*)&h1s[t * 136 + i16 * 8];
        *(short8_t*)(dst + t * 128 + i16 * 8) = v;
    }
}

// ---------------------------------------------------------------------------
// Kernel B (phase 2+3): per block (b,pq), wave w owns rs = 3w..3w+2.
// NO LDS, NO barriers: h1 fragments and W2b read per-lane from global
// (L2-hot, same-XCD swizzle as A). Occupancy VGPR-limited -> high TLP.
// ---------------------------------------------------------------------------
__global__ __launch_bounds__(256) void fused_p2(
    const unsigned short* __restrict__ h1g, const unsigned short* __restrict__ W2b,
    const int* __restrict__ cam, const int* __restrict__ ord,
    const float* __restrict__ b2, const float* __restrict__ W3,
    const float* __restrict__ b3, float* __restrict__ out)
{
    const int idx = blockIdx.x;
    const int swz = (idx & 7) * 192 + (idx >> 3);   // same swizzle as A
    const int bpos = swz / 12, pq = swz - bpos * 12;
    const int b = ord[bpos];

    const int tid = threadIdx.x;
    const int w = tid >> 6, l = tid & 63;
    const int l15 = l & 15, g = l >> 4;
    const int c = cam[b];

    // a2 fragments direct from global h1 tile
    const unsigned short* h1t = h1g + (size_t)(b * 12 + pq) * 8192;
    short8_t a2[4][4];
    #pragma unroll
    for (int mt = 0; mt < 4; ++mt)
        #pragma unroll
        for (int kk = 0; kk < 4; ++kk)
            a2[mt][kk] = *(const short8_t*)(h1t + (16 * mt + l15) * 128 + 32 * kk + 8 * g);

    const unsigned short* W2base = W2b + (size_t)(c * 12 + w * 3) * (H2_ * H1_)
                                 + (size_t)l15 * H1_ + 8 * g;
    short8_t bfr[2][4];
    #pragma unroll
    for (int kk = 0; kk < 4; ++kk)
        bfr[0][kk] = *(const short8_t*)(W2base + kk * 32);

    float w3v[4], b2v[4];
    #pragma unroll
    for (int nt = 0; nt < 4; ++nt) {
        w3v[nt] = W3[c * H2_ + 16 * nt + l15];
        b2v[nt] = b2[c * H2_ + 16 * nt + l15];
    }
    const float b3v = b3[c];
    const int p = pq >> 2, q = pq & 3;

    float s[4][4];
    #pragma unroll
    for (int mt = 0; mt < 4; ++mt) { s[mt][0] = s[mt][1] = s[mt][2] = s[mt][3] = 0.f; }

    // seg = 0..11 : rs_local = seg>>2, nt = seg&3 ; 1-ahead 2-slot prefetch
    #pragma unroll
    for (int seg = 0; seg < 12; ++seg) {
        if (seg < 11) {
            const int ns = seg + 1;
            const unsigned short* nb = W2base + (size_t)(ns >> 2) * (H2_ * H1_)
                                     + (ns & 3) * (16 * H1_);
            #pragma unroll
            for (int kk = 0; kk < 4; ++kk)
                bfr[(seg + 1) & 1][kk] = *(const short8_t*)(nb + kk * 32);
        }
        const int nt = seg & 3;
        #pragma unroll
        for (int mt = 0; mt < 4; ++mt) {
            f32x4 acc2 = (f32x4){0.f, 0.f, 0.f, 0.f};
            #pragma unroll
            for (int kk = 0; kk < 4; ++kk)
                acc2 = __builtin_amdgcn_mfma_f32_16x16x32_bf16(
                    a2[mt][kk], bfr[seg & 1][kk], acc2, 0, 0, 0);
            #pragma unroll
            for (int r = 0; r < 4; ++r)
                s[mt][r] += w3v[nt] * fmaxf(acc2[r] + b2v[nt], 0.f);
        }

        if (nt == 3) {
            const int rs = w * 3 + (seg >> 2);
            const int hrow = p * 3 + (rs >> 2), wcol = q * 4 + (rs & 3);
            #pragma unroll
            for (int mt = 0; mt < 4; ++mt)
                #pragma unroll
                for (int r = 0; r < 4; ++r) {
                    float v = s[mt][r];
                    v += __shfl_xor(v, 1); v += __shfl_xor(v, 2);
                    v += __shfl_xor(v, 4); v += __shfl_xor(v, 8);
                    if (l15 == 0) {
                        const int t = 16 * mt + 4 * g + r;
                        if (t < T_)
                            out[(((size_t)b * T_ + t) * 9 + hrow) * 16 + wcol] =
                                1.f / (1.f + __expf(-(v + b3v)));
                    }
                    s[mt][r] = 0.f;
                }
        }
    }
}

// ---------------------------------------------------------------------------
// fp32 VALU fallback — used only if ws too small
// ---------------------------------------------------------------------------
__global__ __launch_bounds__(256) void fused_decoder_f32(
    const float* __restrict__ x,   const int* __restrict__ cam,
    const float* __restrict__ W1,  const float* __restrict__ b1,
    const float* __restrict__ W2,  const float* __restrict__ b2,
    const float* __restrict__ W3,  const float* __restrict__ b3,
    float* __restrict__ out)
{
    __shared__ float h1s[T_ * H1_];
    __shared__ float stage[8192];

    const int pq  = blockIdx.x;
    const int b   = blockIdx.y;
    const int p   = pq >> 2, q = pq & 3;
    const int tid = threadIdx.x;
    const int c   = cam[b];

    float* xs  = stage;
    float* w1s = stage + 2048;

    const int ig = tid & 31;
    const int tg = tid >> 5;

    float acc[8][4];
    #pragma unroll
    for (int a = 0; a < 8; ++a)
        #pragma unroll
        for (int j = 0; j < 4; ++j) acc[a][j] = 0.f;

    for (int f0 = 0; f0 < F_; f0 += 32) {
        __syncthreads();
        {
            int lane = tid & 63;
            int sub  = tid >> 6;
            if (lane < T_) {
                #pragma unroll
                for (int m = 0; m < 8; ++m) {
                    int kk = sub * 8 + m;
                    xs[kk * 64 + lane] = x[((size_t)b * F_ + f0 + kk) * T_ + lane];
                }
            }
        }
        for (int e = tid; e < 32 * H1_; e += 256) {
            int kk = e >> 7, i = e & 127;
            w1s[e] = W1[(((size_t)c * F_ + f0 + kk) * H1_ + i) * 12 + pq];
        }
        __syncthreads();
        #pragma unroll 8
        for (int kk = 0; kk < 32; ++kk) {
            float4 bv = *(const float4*)&w1s[kk * 128 + ig * 4];
            float4 a0 = *(const float4*)&xs[kk * 64 + tg * 8];
            float4 a1 = *(const float4*)&xs[kk * 64 + tg * 8 + 4];
            float at[8] = {a0.x, a0.y, a0.z, a0.w, a1.x, a1.y, a1.z, a1.w};
            #pragma unroll
            for (int tt = 0; tt < 8; ++tt) {
                acc[tt][0] = fmaf(at[tt], bv.x, acc[tt][0]);
                acc[tt][1] = fmaf(at[tt], bv.y, acc[tt][1]);
                acc[tt][2] = fmaf(at[tt], bv.z, acc[tt][2]);
                acc[tt][3] = fmaf(at[tt], bv.w, acc[tt][3]);
            }
        }
    }
    {
        float4 b1v = *(const float4*)&b1[c * H1_ + ig * 4];
        #pragma unroll
        for (int tt = 0; tt < 8; ++tt) {
            int t = tg * 8 + tt;
            if (t < T_) {
                float4 hv;
                hv.x = fmaxf(acc[tt][0] + b1v.x, 0.f);
                hv.y = fmaxf(acc[tt][1] + b1v.y, 0.f);
                hv.z = fmaxf(acc[tt][2] + b1v.z, 0.f);
                hv.w = fmaxf(acc[tt][3] + b1v.w, 0.f);
                *(float4*)&h1s[t * H1_ + ig * 4] = hv;
            }
        }
    }

    const int lane = tid & 63;
    const int wv   = tid >> 6;
    const float w3v = W3[c * H2_ + lane];
    const float b2v = b2[c * H2_ + lane];
    const float b3v = b3[c];
    float* w2s = stage;

    for (int rs = 0; rs < 12; ++rs) {
        __syncthreads();
        for (int e = tid; e < H1_ * H2_; e += 256) {
            int i = e >> 6, o = e & 63;
            w2s[e] = W2[(((size_t)c * H1_ + i) * H2_ + o) * 12 + rs];
        }
        __syncthreads();

        float acc2[15];
        #pragma unroll
        for (int j = 0; j < 15; ++j) acc2[j] = 0.f;

        for (int i = 0; i < H1_; i += 4) {
            float wa = w2s[(i + 0) * 64 + lane];
            float wb = w2s[(i + 1) * 64 + lane];
            float wc = w2s[(i + 2) * 64 + lane];
            float wd = w2s[(i + 3) * 64 + lane];
            #pragma unroll
            for (int j = 0; j < 15; ++j) {
                float4 h = *(const float4*)&h1s[(wv * 15 + j) * H1_ + i];
                acc2[j] = fmaf(h.x, wa, acc2[j]);
                acc2[j] = fmaf(h.y, wb, acc2[j]);
                acc2[j] = fmaf(h.z, wc, acc2[j]);
                acc2[j] = fmaf(h.w, wd, acc2[j]);
            }
        }

        const int r = rs >> 2, s = rs & 3;
        const int hrow = p * 3 + r, wcol = q * 4 + s;
        #pragma unroll
        for (int j = 0; j < 15; ++j) {
            float y = w3v * fmaxf(acc2[j] + b2v, 0.f);
            #pragma unroll
            for (int m = 32; m > 0; m >>= 1) y += __shfl_xor(y, m, 64);
            if (lane == j) {
                int t = wv * 15 + j;
                float v = y + b3v;
                out[(((size_t)b * T_ + t) * 9 + hrow) * 16 + wcol] = 1.f / (1.f + __expf(-v));
            }
        }
    }
}

// ---------------------------------------------------------------------------
extern "C" void kernel_launch(void* const* d_in, const int* in_sizes, int n_in,
                              void* d_out, int out_size, void* d_ws, size_t ws_size,
                              hipStream_t stream) {
    const float* x   = (const float*)d_in[0];
    const int*   cam = (const int*)  d_in[1];
    const float* W1  = (const float*)d_in[2];
    const float* b1  = (const float*)d_in[3];
    const float* W2  = (const float*)d_in[4];
    const float* b2  = (const float*)d_in[5];
    const float* W3  = (const float*)d_in[6];
    const float* b3  = (const float*)d_in[7];
    float* outp = (float*)d_out;

    const size_t n_xT  = (size_t)B_ * 32768;            //  4,194,304 (swizzled A images)
    const size_t n_w1s = (size_t)C_ * 12 * 65536;       // 11,796,480 (swizzled B images)
    const size_t n_w2b = (size_t)C_ * 12 * H2_ * H1_;   //  1,474,560
    const size_t n_h1  = (size_t)B_ * 12 * 8192;        // 12,582,912 (h1 tiles)
    const size_t needed = (n_xT + n_w1s + n_w2b + n_h1) * sizeof(unsigned short)
                        + B_ * sizeof(int);

    if (d_ws != nullptr && ws_size >= needed) {
        unsigned short* xTs = (unsigned short*)d_ws;
        unsigned short* W1p = xTs + n_xT;
        unsigned short* W2p = W1p + n_w1s;
        unsigned short* h1g = W2p + n_w2b;
        int* ord = (int*)(h1g + n_h1);
        make_order<<<1, 128, 0, stream>>>(cam, ord);
        repack_x <<<dim3(4, B_), 256, 0, stream>>>(x, xTs);
        repack_w1<<<dim3(F_ / 32, H1_ / 32, C_), 256, 0, stream>>>(W1, W1p);
        repack_w2<<<dim3(H1_ / 32, H2_ / 32, C_), 256, 0, stream>>>(W2, W2p);
        fused_p1<<<dim3(12 * B_), 256, 0, stream>>>(xTs, W1p, cam, ord, b1, h1g);
        fused_p2<<<dim3(12 * B_), 256, 0, stream>>>(h1g, W2p, cam, ord, b2, W3, b3, outp);
    } else {
        fused_decoder_f32<<<dim3(12, B_), 256, 0, stream>>>(
            x, cam, W1, b1, W2, b2, W3, b3, outp);
    }
}

// Round 14
// 98.523 us; speedup vs baseline: 1.1583x; 1.1583x over previous
//
#include <hip/hip_runtime.h>
#include <hip/hip_bf16.h>
#include <cstdint>

// Problem constants
#define B_  128
#define F_  512
#define T_  60
#define C_  15
#define H1_ 128
#define H2_ 64

typedef short short8_t __attribute__((ext_vector_type(8)));   // 8 bf16 (4 VGPR)
typedef float f32x4    __attribute__((ext_vector_type(4)));   // MFMA acc

static __device__ __forceinline__ unsigned short f2bf(float f) {
    union { float f; uint32_t u; } v; v.f = f;
    uint32_t r = v.u + 0x7FFF + ((v.u >> 16) & 1);   // RNE
    return (unsigned short)(r >> 16);
}

// async 16B global -> LDS DMA (dest = wave-uniform base + lane*16)
static __device__ __forceinline__ void async_cp16(const unsigned short* g, unsigned short* l) {
    __builtin_amdgcn_global_load_lds(
        (const __attribute__((address_space(1))) unsigned int*)g,
        (__attribute__((address_space(3))) unsigned int*)l, 16, 0, 0);
}

// ---------------------------------------------------------------------------
// Camera-sort: ord[rank] = b, stable sort of b by cam[b]. 1 block, 128 thr.
// ---------------------------------------------------------------------------
__global__ __launch_bounds__(128) void make_order(const int* __restrict__ cam,
                                                  int* __restrict__ ord) {
    __shared__ int cs[B_];
    const int b = threadIdx.x;
    cs[b] = cam[b];
    __syncthreads();
    const int cb = cs[b];
    int rank = 0;
    #pragma unroll 16
    for (int j = 0; j < B_; ++j) {
        int cj = cs[j];
        rank += (cj < cb || (cj == cb && j < b)) ? 1 : 0;
    }
    ord[rank] = b;
}

// ---------------------------------------------------------------------------
// Repack x (B,F,T) f32 -> xTs (B, 8 kc-chunks, swizzled 64x64 LDS image) bf16.
// unit (kc, row t, cc): holds k = kc*64 + (cc ^ (t&7))*8 .. +8
// ---------------------------------------------------------------------------
__global__ __launch_bounds__(256) void repack_x(const float* __restrict__ x,
                                                unsigned short* __restrict__ xTs) {
    __shared__ float xs[128][61];
    const int f0 = blockIdx.x * 128, b = blockIdx.y, tid = threadIdx.x;
    #pragma unroll
    for (int it = 0; it < 32; ++it) {
        int idx = tid + it * 256;          // 128*64
        int fl = idx >> 6, t = idx & 63;
        if (t < T_) xs[fl][t] = x[((size_t)b * F_ + f0 + fl) * T_ + t];
    }
    __syncthreads();
    #pragma unroll
    for (int it = 0; it < 8; ++it) {
        int idx = tid + it * 256;          // 64*32
        int t = idx >> 5, f4 = (idx & 31) * 4;
        ushort4 o;
        o.x = (t < T_) ? f2bf(xs[f4 + 0][t]) : 0;
        o.y = (t < T_) ? f2bf(xs[f4 + 1][t]) : 0;
        o.z = (t < T_) ? f2bf(xs[f4 + 2][t]) : 0;
        o.w = (t < T_) ? f2bf(xs[f4 + 3][t]) : 0;
        const int f = f0 + f4;
        const int kc = f >> 6, within = f & 63;
        const int cc = (within >> 3) ^ (t & 7), half = (within >> 2) & 1;
        *(ushort4*)(xTs + (size_t)b * 32768 + kc * 4096 + t * 64 + cc * 8 + half * 4) = o;
    }
}

// ---------------------------------------------------------------------------
// Repack W1 (C,F,H1,3,4) f32 -> W1s[(c*12+pq)][kc][swizzled 128x64 image] bf16
//   slice = 65536 ush; kc chunk = 8192 ush; unit k = kc*64 + (cc^(i&7))*8..+8
// ---------------------------------------------------------------------------
__global__ __launch_bounds__(256) void repack_w1(const float* __restrict__ W1,
                                                 unsigned short* __restrict__ W1s) {
    __shared__ float ls[32][384];
    const int f0 = blockIdx.x * 32, i0 = blockIdx.y * 32, c = blockIdx.z;
    const int tid = threadIdx.x;
    #pragma unroll
    for (int it = 0; it < 12; ++it) {
        int idx = tid + it * 256;              // 3072 float4
        int fl = idx / 96, r = idx - fl * 96;
        float4 v = *(const float4*)(W1 + ((size_t)(c * F_ + f0 + fl)) * (H1_ * 12)
                                       + (size_t)i0 * 12 + r * 4);
        *(float4*)&ls[fl][r * 4] = v;
    }
    __syncthreads();
    const int i_l = tid >> 3, f_l = (tid & 7) * 4;
    const int i = i0 + i_l, f = f0 + f_l;
    const int kc = f >> 6, within = f & 63;
    const int cc = (within >> 3) ^ (i & 7), half = (within >> 2) & 1;
    #pragma unroll
    for (int pq = 0; pq < 12; ++pq) {
        ushort4 o;
        o.x = f2bf(ls[f_l + 0][i_l * 12 + pq]);
        o.y = f2bf(ls[f_l + 1][i_l * 12 + pq]);
        o.z = f2bf(ls[f_l + 2][i_l * 12 + pq]);
        o.w = f2bf(ls[f_l + 3][i_l * 12 + pq]);
        *(ushort4*)(W1s + (size_t)(c * 12 + pq) * 65536
                        + kc * 8192 + i * 64 + cc * 8 + half * 4) = o;
    }
}

// ---------------------------------------------------------------------------
// Repack W2 (C,H1,H2,3,4) f32 -> W2f FRAGMENT-MAJOR bf16:
//   tile (c,rs) = 16 frags x 512 ush (8192 ush). frag f = nt*4+kk; lane l
//   holds 8 ush: o = 16*nt + (l&15), k(=i) = 32*kk + 8*(l>>4) .. +8.
//   p2's wave load of one frag = 64 lanes x 16B contiguous 1KB.
// ---------------------------------------------------------------------------
__global__ __launch_bounds__(256) void repack_w2(const float* __restrict__ W2,
                                                 unsigned short* __restrict__ W2f) {
    __shared__ float ls[32][384];
    const int i0 = blockIdx.x * 32, o0 = blockIdx.y * 32, c = blockIdx.z;
    const int tid = threadIdx.x;
    #pragma unroll
    for (int it = 0; it < 12; ++it) {
        int idx = tid + it * 256;
        int il = idx / 96, r = idx - il * 96;
        float4 v = *(const float4*)(W2 + ((size_t)(c * H1_ + i0 + il)) * (H2_ * 12)
                                       + (size_t)o0 * 12 + r * 4);
        *(float4*)&ls[il][r * 4] = v;
    }
    __syncthreads();
    const int o_l = tid >> 3, i_l = (tid & 7) * 4;   // o_l 0..31, i_l {0,4,..,28}
    const int o  = o0 + o_l;
    const int nt = o >> 4, l15 = o & 15;
    const int lane = l15 + 16 * ((i_l >> 3) & 3);
    const int kk  = i0 >> 5;
    const int pos = i_l & 7;                          // 0 or 4
    #pragma unroll
    for (int rs = 0; rs < 12; ++rs) {
        ushort4 v;
        v.x = f2bf(ls[i_l + 0][o_l * 12 + rs]);
        v.y = f2bf(ls[i_l + 1][o_l * 12 + rs]);
        v.z = f2bf(ls[i_l + 2][o_l * 12 + rs]);
        v.w = f2bf(ls[i_l + 3][o_l * 12 + rs]);
        *(ushort4*)(W2f + ((size_t)(c * 12 + rs) * 16 + nt * 4 + kk) * 512
                        + lane * 8 + pos) = v;
    }
}

// ---------------------------------------------------------------------------
// Kernel A (phase 1): h1(64x128) = relu(xT * W1^T + b1) -> h1f FRAGMENT-MAJOR
//   global bf16: tile (b,pq) = 16 frags x 512 ush; frag f = mt*4+kk; lane l:
//   t = 16*mt + (l&15), i = 32*kk + 8*(l>>4) .. +8.
// R10's staging loop (2-deep LDS DMA, counted vmcnt, raw barriers).
// ---------------------------------------------------------------------------
__global__ __launch_bounds__(256) void fused_p1(
    const unsigned short* __restrict__ xTs, const unsigned short* __restrict__ W1s,
    const int* __restrict__ cam, const int* __restrict__ ord,
    const float* __restrict__ b1, unsigned short* __restrict__ h1g)
{
    __shared__ __align__(16) unsigned short smem[24576];   // 48 KB

    const int idx = blockIdx.x;
    const int swz = (idx & 7) * 192 + (idx >> 3);   // bijective XCD swizzle
    const int bpos = swz / 12, pq = swz - bpos * 12;
    const int b = ord[bpos];

    const int tid = threadIdx.x;
    const int w = tid >> 6, l = tid & 63;
    const int l15 = l & 15, g = l >> 4;
    const int c = cam[b];

    const unsigned short* xchunk = xTs + (size_t)b * 32768;             // 8 x 4096
    const unsigned short* wchunk = W1s + (size_t)(c * 12 + pq) * 65536; // 8 x 8192

    #define STAGE1(kc, buf)                                                       \
        {                                                                         \
            _Pragma("unroll")                                                     \
            for (int k = 0; k < 2; ++k)                                           \
                async_cp16(xchunk + (kc) * 4096 + (w * 2 + k) * 512 + l * 8,      \
                           smem + (buf) * 12288 + (w * 2 + k) * 512 + l * 8);     \
            _Pragma("unroll")                                                     \
            for (int k = 0; k < 4; ++k)                                           \
                async_cp16(wchunk + (kc) * 8192 + (w * 4 + k) * 512 + l * 8,      \
                           smem + (buf) * 12288 + 4096 + (w * 4 + k) * 512 + l * 8); \
        }

    f32x4 acc1[4][2];
    #pragma unroll
    for (int mt = 0; mt < 4; ++mt) {
        acc1[mt][0] = (f32x4){0.f, 0.f, 0.f, 0.f};
        acc1[mt][1] = (f32x4){0.f, 0.f, 0.f, 0.f};
    }

    STAGE1(0, 0);
    STAGE1(1, 1);

    const int sxor = (l15 & 7);
    #pragma unroll
    for (int kc = 0; kc < 8; ++kc) {
        if (kc < 7) { asm volatile("s_waitcnt vmcnt(6)" ::: "memory"); }
        else        { asm volatile("s_waitcnt vmcnt(0)" ::: "memory"); }
        __builtin_amdgcn_s_barrier();
        asm volatile("" ::: "memory");

        const int base = (kc & 1) * 12288;
        #pragma unroll
        for (int kk2 = 0; kk2 < 2; ++kk2) {
            const int cc = (kk2 * 4 + g) ^ sxor;
            short8_t af[4], bf[2];
            #pragma unroll
            for (int mt = 0; mt < 4; ++mt)
                af[mt] = *(const short8_t*)(smem + base + (16 * mt + l15) * 64 + cc * 8);
            #pragma unroll
            for (int ni = 0; ni < 2; ++ni)
                bf[ni] = *(const short8_t*)(smem + base + 4096
                                            + (32 * w + 16 * ni + l15) * 64 + cc * 8);
            #pragma unroll
            for (int mt = 0; mt < 4; ++mt)
                #pragma unroll
                for (int ni = 0; ni < 2; ++ni)
                    acc1[mt][ni] = __builtin_amdgcn_mfma_f32_16x16x32_bf16(
                        af[mt], bf[ni], acc1[mt][ni], 0, 0, 0);
        }

        asm volatile("" ::: "memory");
        __builtin_amdgcn_s_barrier();
        if (kc < 6) STAGE1(kc + 2, kc & 1);
    }
    #undef STAGE1

    // bias + relu -> h1s [64][136] (bank-staggered)
    unsigned short* h1s = smem;
    #pragma unroll
    for (int ni = 0; ni < 2; ++ni) {
        const int i = 32 * w + 16 * ni + l15;
        const float b1v = b1[c * H1_ + i];
        #pragma unroll
        for (int mt = 0; mt < 4; ++mt)
            #pragma unroll
            for (int r = 0; r < 4; ++r) {
                float h = acc1[mt][ni][r] + b1v;
                h = h > 0.f ? h : 0.f;
                h1s[(16 * mt + 4 * g + r) * 136 + i] = f2bf(h);
            }
    }
    __syncthreads();

    // fragment-major writeout: unit u -> frag f = u>>6 (mt=f>>2, kk=f&3),
    // lane ll = u&63: src (t = 16mt + ll&15, i = 32kk + 8*(ll>>4)).
    unsigned short* dst = h1g + (size_t)(b * 12 + pq) * 8192;
    #pragma unroll
    for (int it = 0; it < 4; ++it) {
        int u = tid + it * 256;            // 0..1023
        int f = u >> 6, ll = u & 63;
        int t = (f >> 2) * 16 + (ll & 15);
        int i = (f & 3) * 32 + (ll >> 4) * 8;
        short8_t v = *(const short8_t*)&h1s[t * 136 + i];
        *(short8_t*)(dst + f * 512 + ll * 8) = v;
    }
}

// ---------------------------------------------------------------------------
// Kernel B (phase 2+3): per block (b,pq), wave w owns rs = 3w..3w+2.
// NO LDS, NO barriers. ALL loads fragment-major -> 1KB coalesced per wave.
// W2 prefetch 2-ahead / 3-slot.
// ---------------------------------------------------------------------------
__global__ __launch_bounds__(256) void fused_p2(
    const unsigned short* __restrict__ h1g, const unsigned short* __restrict__ W2f,
    const int* __restrict__ cam, const int* __restrict__ ord,
    const float* __restrict__ b2, const float* __restrict__ W3,
    const float* __restrict__ b3, float* __restrict__ out)
{
    const int idx = blockIdx.x;
    const int swz = (idx & 7) * 192 + (idx >> 3);   // same swizzle as A
    const int bpos = swz / 12, pq = swz - bpos * 12;
    const int b = ord[bpos];

    const int tid = threadIdx.x;
    const int w = tid >> 6, l = tid & 63;
    const int l15 = l & 15, g = l >> 4;
    const int c = cam[b];

    // a2 fragments: 16 coalesced 1KB wave loads
    const unsigned short* h1f = h1g + (size_t)(b * 12 + pq) * 8192;
    short8_t a2[4][4];
    #pragma unroll
    for (int mt = 0; mt < 4; ++mt)
        #pragma unroll
        for (int kk = 0; kk < 4; ++kk)
            a2[mt][kk] = *(const short8_t*)(h1f + (mt * 4 + kk) * 512 + l * 8);

    // W2 fragment tiles: wave's 3 rs tiles at W2base + rsl*8192
    const unsigned short* W2base = W2f + (size_t)(c * 12 + w * 3) * 8192;

    short8_t bfr[3][4];
    #pragma unroll
    for (int ps = 0; ps < 2; ++ps) {     // prefetch segs 0,1
        const unsigned short* nb = W2base + (ps >> 2) * 8192 + ((ps & 3) * 4) * 512;
        #pragma unroll
        for (int kk = 0; kk < 4; ++kk)
            bfr[ps][kk] = *(const short8_t*)(nb + kk * 512 + l * 8);
    }

    float w3v[4], b2v[4];
    #pragma unroll
    for (int nt = 0; nt < 4; ++nt) {
        w3v[nt] = W3[c * H2_ + 16 * nt + l15];
        b2v[nt] = b2[c * H2_ + 16 * nt + l15];
    }
    const float b3v = b3[c];
    const int p = pq >> 2, q = pq & 3;

    float s[4][4];
    #pragma unroll
    for (int mt = 0; mt < 4; ++mt) { s[mt][0] = s[mt][1] = s[mt][2] = s[mt][3] = 0.f; }

    // seg = 0..11 : rs_local = seg>>2, nt = seg&3 ; 2-ahead 3-slot prefetch
    #pragma unroll
    for (int seg = 0; seg < 12; ++seg) {
        if (seg < 10) {
            const int ns = seg + 2;
            const unsigned short* nb = W2base + (ns >> 2) * 8192 + ((ns & 3) * 4) * 512;
            #pragma unroll
            for (int kk = 0; kk < 4; ++kk)
                bfr[ns % 3][kk] = *(const short8_t*)(nb + kk * 512 + l * 8);
        }
        const int nt = seg & 3;
        #pragma unroll
        for (int mt = 0; mt < 4; ++mt) {
            f32x4 acc2 = (f32x4){0.f, 0.f, 0.f, 0.f};
            #pragma unroll
            for (int kk = 0; kk < 4; ++kk)
                acc2 = __builtin_amdgcn_mfma_f32_16x16x32_bf16(
                    a2[mt][kk], bfr[seg % 3][kk], acc2, 0, 0, 0);
            #pragma unroll
            for (int r = 0; r < 4; ++r)
                s[mt][r] += w3v[nt] * fmaxf(acc2[r] + b2v[nt], 0.f);
        }

        if (nt == 3) {
            const int rs = w * 3 + (seg >> 2);
            const int hrow = p * 3 + (rs >> 2), wcol = q * 4 + (rs & 3);
            #pragma unroll
            for (int mt = 0; mt < 4; ++mt)
                #pragma unroll
                for (int r = 0; r < 4; ++r) {
                    float v = s[mt][r];
                    v += __shfl_xor(v, 1); v += __shfl_xor(v, 2);
                    v += __shfl_xor(v, 4); v += __shfl_xor(v, 8);
                    if (l15 == 0) {
                        const int t = 16 * mt + 4 * g + r;
                        if (t < T_)
                            out[(((size_t)b * T_ + t) * 9 + hrow) * 16 + wcol] =
                                1.f / (1.f + __expf(-(v + b3v)));
                    }
                    s[mt][r] = 0.f;
                }
        }
    }
}

// ---------------------------------------------------------------------------
// fp32 VALU fallback — used only if ws too small
// ---------------------------------------------------------------------------
__global__ __launch_bounds__(256) void fused_decoder_f32(
    const float* __restrict__ x,   const int* __restrict__ cam,
    const float* __restrict__ W1,  const float* __restrict__ b1,
    const float* __restrict__ W2,  const float* __restrict__ b2,
    const float* __restrict__ W3,  const float* __restrict__ b3,
    float* __restrict__ out)
{
    __shared__ float h1s[T_ * H1_];
    __shared__ float stage[8192];

    const int pq  = blockIdx.x;
    const int b   = blockIdx.y;
    const int p   = pq >> 2, q = pq & 3;
    const int tid = threadIdx.x;
    const int c   = cam[b];

    float* xs  = stage;
    float* w1s = stage + 2048;

    const int ig = tid & 31;
    const int tg = tid >> 5;

    float acc[8][4];
    #pragma unroll
    for (int a = 0; a < 8; ++a)
        #pragma unroll
        for (int j = 0; j < 4; ++j) acc[a][j] = 0.f;

    for (int f0 = 0; f0 < F_; f0 += 32) {
        __syncthreads();
        {
            int lane = tid & 63;
            int sub  = tid >> 6;
            if (lane < T_) {
                #pragma unroll
                for (int m = 0; m < 8; ++m) {
                    int kk = sub * 8 + m;
                    xs[kk * 64 + lane] = x[((size_t)b * F_ + f0 + kk) * T_ + lane];
                }
            }
        }
        for (int e = tid; e < 32 * H1_; e += 256) {
            int kk = e >> 7, i = e & 127;
            w1s[e] = W1[(((size_t)c * F_ + f0 + kk) * H1_ + i) * 12 + pq];
        }
        __syncthreads();
        #pragma unroll 8
        for (int kk = 0; kk < 32; ++kk) {
            float4 bv = *(const float4*)&w1s[kk * 128 + ig * 4];
            float4 a0 = *(const float4*)&xs[kk * 64 + tg * 8];
            float4 a1 = *(const float4*)&xs[kk * 64 + tg * 8 + 4];
            float at[8] = {a0.x, a0.y, a0.z, a0.w, a1.x, a1.y, a1.z, a1.w};
            #pragma unroll
            for (int tt = 0; tt < 8; ++tt) {
                acc[tt][0] = fmaf(at[tt], bv.x, acc[tt][0]);
                acc[tt][1] = fmaf(at[tt], bv.y, acc[tt][1]);
                acc[tt][2] = fmaf(at[tt], bv.z, acc[tt][2]);
                acc[tt][3] = fmaf(at[tt], bv.w, acc[tt][3]);
            }
        }
    }
    {
        float4 b1v = *(const float4*)&b1[c * H1_ + ig * 4];
        #pragma unroll
        for (int tt = 0; tt < 8; ++tt) {
            int t = tg * 8 + tt;
            if (t < T_) {
                float4 hv;
                hv.x = fmaxf(acc[tt][0] + b1v.x, 0.f);
                hv.y = fmaxf(acc[tt][1] + b1v.y, 0.f);
                hv.z = fmaxf(acc[tt][2] + b1v.z, 0.f);
                hv.w = fmaxf(acc[tt][3] + b1v.w, 0.f);
                *(float4*)&h1s[t * H1_ + ig * 4] = hv;
            }
        }
    }

    const int lane = tid & 63;
    const int wv   = tid >> 6;
    const float w3v = W3[c * H2_ + lane];
    const float b2v = b2[c * H2_ + lane];
    const float b3v = b3[c];
    float* w2s = stage;

    for (int rs = 0; rs < 12; ++rs) {
        __syncthreads();
        for (int e = tid; e < H1_ * H2_; e += 256) {
            int i = e >> 6, o = e & 63;
            w2s[e] = W2[(((size_t)c * H1_ + i) * H2_ + o) * 12 + rs];
        }
        __syncthreads();

        float acc2[15];
        #pragma unroll
        for (int j = 0; j < 15; ++j) acc2[j] = 0.f;

        for (int i = 0; i < H1_; i += 4) {
            float wa = w2s[(i + 0) * 64 + lane];
            float wb = w2s[(i + 1) * 64 + lane];
            float wc = w2s[(i + 2) * 64 + lane];
            float wd = w2s[(i + 3) * 64 + lane];
            #pragma unroll
            for (int j = 0; j < 15; ++j) {
                float4 h = *(const float4*)&h1s[(wv * 15 + j) * H1_ + i];
                acc2[j] = fmaf(h.x, wa, acc2[j]);
                acc2[j] = fmaf(h.y, wb, acc2[j]);
                acc2[j] = fmaf(h.z, wc, acc2[j]);
                acc2[j] = fmaf(h.w, wd, acc2[j]);
            }
        }

        const int r = rs >> 2, s = rs & 3;
        const int hrow = p * 3 + r, wcol = q * 4 + s;
        #pragma unroll
        for (int j = 0; j < 15; ++j) {
            float y = w3v * fmaxf(acc2[j] + b2v, 0.f);
            #pragma unroll
            for (int m = 32; m > 0; m >>= 1) y += __shfl_xor(y, m, 64);
            if (lane == j) {
                int t = wv * 15 + j;
                float v = y + b3v;
                out[(((size_t)b * T_ + t) * 9 + hrow) * 16 + wcol] = 1.f / (1.f + __expf(-v));
            }
        }
    }
}

// ---------------------------------------------------------------------------
extern "C" void kernel_launch(void* const* d_in, const int* in_sizes, int n_in,
                              void* d_out, int out_size, void* d_ws, size_t ws_size,
                              hipStream_t stream) {
    const float* x   = (const float*)d_in[0];
    const int*   cam = (const int*)  d_in[1];
    const float* W1  = (const float*)d_in[2];
    const float* b1  = (const float*)d_in[3];
    const float* W2  = (const float*)d_in[4];
    const float* b2  = (const float*)d_in[5];
    const float* W3  = (const float*)d_in[6];
    const float* b3  = (const float*)d_in[7];
    float* outp = (float*)d_out;

    const size_t n_xT  = (size_t)B_ * 32768;            //  4,194,304 (swizzled A images)
    const size_t n_w1s = (size_t)C_ * 12 * 65536;       // 11,796,480 (swizzled B images)
    const size_t n_w2f = (size_t)C_ * 12 * 16 * 512;    //  1,474,560 (fragment-major)
    const size_t n_h1  = (size_t)B_ * 12 * 8192;        // 12,582,912 (fragment-major tiles)
    const size_t needed = (n_xT + n_w1s + n_w2f + n_h1) * sizeof(unsigned short)
                        + B_ * sizeof(int);

    if (d_ws != nullptr && ws_size >= needed) {
        unsigned short* xTs = (unsigned short*)d_ws;
        unsigned short* W1p = xTs + n_xT;
        unsigned short* W2p = W1p + n_w1s;
        unsigned short* h1g = W2p + n_w2f;
        int* ord = (int*)(h1g + n_h1);
        make_order<<<1, 128, 0, stream>>>(cam, ord);
        repack_x <<<dim3(4, B_), 256, 0, stream>>>(x, xTs);
        repack_w1<<<dim3(F_ / 32, H1_ / 32, C_), 256, 0, stream>>>(W1, W1p);
        repack_w2<<<dim3(H1_ / 32, H2_ / 32, C_), 256, 0, stream>>>(W2, W2p);
        fused_p1<<<dim3(12 * B_), 256, 0, stream>>>(xTs, W1p, cam, ord, b1, h1g);
        fused_p2<<<dim3(12 * B_), 256, 0, stream>>>(h1g, W2p, cam, ord, b2, W3, b3, outp);
    } else {
        fused_decoder_f32<<<dim3(12, B_), 256, 0, stream>>>(
            x, cam, W1, b1, W2, b2, W3, b3, outp);
    }
}

// Round 15
// 76.914 us; speedup vs baseline: 1.4837x; 1.2810x over previous
//
#include <hip/hip_runtime.h>
#include <hip/hip_bf16.h>
#include <cstdint>

// Problem constants
#define B_  128
#define F_  512
#define T_  60
#define C_  15
#define H1_ 128
#define H2_ 64

typedef short short8_t __attribute__((ext_vector_type(8)));   // 8 bf16 (4 VGPR)
typedef float f32x4    __attribute__((ext_vector_type(4)));   // MFMA acc

static __device__ __forceinline__ unsigned short f2bf(float f) {
    union { float f; uint32_t u; } v; v.f = f;
    uint32_t r = v.u + 0x7FFF + ((v.u >> 16) & 1);   // RNE
    return (unsigned short)(r >> 16);
}

// async 16B global -> LDS DMA (dest = wave-uniform base + lane*16)
static __device__ __forceinline__ void async_cp16(const unsigned short* g, unsigned short* l) {
    __builtin_amdgcn_global_load_lds(
        (const __attribute__((address_space(1))) unsigned int*)g,
        (__attribute__((address_space(3))) unsigned int*)l, 16, 0, 0);
}

// ---------------------------------------------------------------------------
// Camera-sort: ord[rank] = b, stable sort of b by cam[b]. 1 block, 128 thr.
// ---------------------------------------------------------------------------
__global__ __launch_bounds__(128) void make_order(const int* __restrict__ cam,
                                                  int* __restrict__ ord) {
    __shared__ int cs[B_];
    const int b = threadIdx.x;
    cs[b] = cam[b];
    __syncthreads();
    const int cb = cs[b];
    int rank = 0;
    #pragma unroll 16
    for (int j = 0; j < B_; ++j) {
        int cj = cs[j];
        rank += (cj < cb || (cj == cb && j < b)) ? 1 : 0;
    }
    ord[rank] = b;
}

// ---------------------------------------------------------------------------
// Repack x (B,F,T) f32 -> xTs (B, 8 kc-chunks, swizzled 64x64 LDS image) bf16.
// unit (kc, row t, cc): holds k = kc*64 + (cc ^ (t&7))*8 .. +8
// ---------------------------------------------------------------------------
__global__ __launch_bounds__(256) void repack_x(const float* __restrict__ x,
                                                unsigned short* __restrict__ xTs) {
    __shared__ float xs[128][61];
    const int f0 = blockIdx.x * 128, b = blockIdx.y, tid = threadIdx.x;
    #pragma unroll
    for (int it = 0; it < 32; ++it) {
        int idx = tid + it * 256;          // 128*64
        int fl = idx >> 6, t = idx & 63;
        if (t < T_) xs[fl][t] = x[((size_t)b * F_ + f0 + fl) * T_ + t];
    }
    __syncthreads();
    #pragma unroll
    for (int it = 0; it < 8; ++it) {
        int idx = tid + it * 256;          // 64*32
        int t = idx >> 5, f4 = (idx & 31) * 4;
        ushort4 o;
        o.x = (t < T_) ? f2bf(xs[f4 + 0][t]) : 0;
        o.y = (t < T_) ? f2bf(xs[f4 + 1][t]) : 0;
        o.z = (t < T_) ? f2bf(xs[f4 + 2][t]) : 0;
        o.w = (t < T_) ? f2bf(xs[f4 + 3][t]) : 0;
        const int f = f0 + f4;
        const int kc = f >> 6, within = f & 63;
        const int cc = (within >> 3) ^ (t & 7), half = (within >> 2) & 1;
        *(ushort4*)(xTs + (size_t)b * 32768 + kc * 4096 + t * 64 + cc * 8 + half * 4) = o;
    }
}

// ---------------------------------------------------------------------------
// Repack W1 (C,F,H1,3,4) f32 -> W1s[(c*12+pq)][kc][swizzled 128x64 image] bf16
//   slice = 65536 ush; kc chunk = 8192 ush; unit k = kc*64 + (cc^(i&7))*8..+8
// ---------------------------------------------------------------------------
__global__ __launch_bounds__(256) void repack_w1(const float* __restrict__ W1,
                                                 unsigned short* __restrict__ W1s) {
    __shared__ float ls[32][384];
    const int f0 = blockIdx.x * 32, i0 = blockIdx.y * 32, c = blockIdx.z;
    const int tid = threadIdx.x;
    #pragma unroll
    for (int it = 0; it < 12; ++it) {
        int idx = tid + it * 256;              // 3072 float4
        int fl = idx / 96, r = idx - fl * 96;
        float4 v = *(const float4*)(W1 + ((size_t)(c * F_ + f0 + fl)) * (H1_ * 12)
                                       + (size_t)i0 * 12 + r * 4);
        *(float4*)&ls[fl][r * 4] = v;
    }
    __syncthreads();
    const int i_l = tid >> 3, f_l = (tid & 7) * 4;
    const int i = i0 + i_l, f = f0 + f_l;
    const int kc = f >> 6, within = f & 63;
    const int cc = (within >> 3) ^ (i & 7), half = (within >> 2) & 1;
    #pragma unroll
    for (int pq = 0; pq < 12; ++pq) {
        ushort4 o;
        o.x = f2bf(ls[f_l + 0][i_l * 12 + pq]);
        o.y = f2bf(ls[f_l + 1][i_l * 12 + pq]);
        o.z = f2bf(ls[f_l + 2][i_l * 12 + pq]);
        o.w = f2bf(ls[f_l + 3][i_l * 12 + pq]);
        *(ushort4*)(W1s + (size_t)(c * 12 + pq) * 65536
                        + kc * 8192 + i * 64 + cc * 8 + half * 4) = o;
    }
}

// ---------------------------------------------------------------------------
// Repack W2 (C,H1,H2,3,4) f32 -> W2f FRAGMENT-MAJOR bf16:
//   tile (c,rs) = 16 frags x 512 ush (8192 ush). frag f = nt*4+kk; lane l
//   holds 8 ush: o = 16*nt + (l&15), k(=i) = 32*kk + 8*(l>>4) .. +8.
// ---------------------------------------------------------------------------
__global__ __launch_bounds__(256) void repack_w2(const float* __restrict__ W2,
                                                 unsigned short* __restrict__ W2f) {
    __shared__ float ls[32][384];
    const int i0 = blockIdx.x * 32, o0 = blockIdx.y * 32, c = blockIdx.z;
    const int tid = threadIdx.x;
    #pragma unroll
    for (int it = 0; it < 12; ++it) {
        int idx = tid + it * 256;
        int il = idx / 96, r = idx - il * 96;
        float4 v = *(const float4*)(W2 + ((size_t)(c * H1_ + i0 + il)) * (H2_ * 12)
                                       + (size_t)o0 * 12 + r * 4);
        *(float4*)&ls[il][r * 4] = v;
    }
    __syncthreads();
    const int o_l = tid >> 3, i_l = (tid & 7) * 4;   // o_l 0..31, i_l {0,4,..,28}
    const int o  = o0 + o_l;
    const int nt = o >> 4, l15 = o & 15;
    const int lane = l15 + 16 * ((i_l >> 3) & 3);
    const int kk  = i0 >> 5;
    const int pos = i_l & 7;                          // 0 or 4
    #pragma unroll
    for (int rs = 0; rs < 12; ++rs) {
        ushort4 v;
        v.x = f2bf(ls[i_l + 0][o_l * 12 + rs]);
        v.y = f2bf(ls[i_l + 1][o_l * 12 + rs]);
        v.z = f2bf(ls[i_l + 2][o_l * 12 + rs]);
        v.w = f2bf(ls[i_l + 3][o_l * 12 + rs]);
        *(ushort4*)(W2f + ((size_t)(c * 12 + rs) * 16 + nt * 4 + kk) * 512
                        + lane * 8 + pos) = v;
    }
}

// ---------------------------------------------------------------------------
// Kernel A (phase 1): h1(64x128) = relu(xT * W1^T + b1) -> h1f FRAGMENT-MAJOR
//   global bf16: tile (b,pq) = 16 frags x 512 ush; frag f = mt*4+kk; lane l:
//   t = 16*mt + (l&15), i = 32*kk + 8*(l>>4) .. +8.
// ---------------------------------------------------------------------------
__global__ __launch_bounds__(256) void fused_p1(
    const unsigned short* __restrict__ xTs, const unsigned short* __restrict__ W1s,
    const int* __restrict__ cam, const int* __restrict__ ord,
    const float* __restrict__ b1, unsigned short* __restrict__ h1g)
{
    __shared__ __align__(16) unsigned short smem[24576];   // 48 KB

    const int idx = blockIdx.x;
    const int swz = (idx & 7) * 192 + (idx >> 3);   // bijective XCD swizzle
    const int bpos = swz / 12, pq = swz - bpos * 12;
    const int b = ord[bpos];

    const int tid = threadIdx.x;
    const int w = tid >> 6, l = tid & 63;
    const int l15 = l & 15, g = l >> 4;
    const int c = cam[b];

    const unsigned short* xchunk = xTs + (size_t)b * 32768;             // 8 x 4096
    const unsigned short* wchunk = W1s + (size_t)(c * 12 + pq) * 65536; // 8 x 8192

    #define STAGE1(kc, buf)                                                       \
        {                                                                         \
            _Pragma("unroll")                                                     \
            for (int k = 0; k < 2; ++k)                                           \
                async_cp16(xchunk + (kc) * 4096 + (w * 2 + k) * 512 + l * 8,      \
                           smem + (buf) * 12288 + (w * 2 + k) * 512 + l * 8);     \
            _Pragma("unroll")                                                     \
            for (int k = 0; k < 4; ++k)                                           \
                async_cp16(wchunk + (kc) * 8192 + (w * 4 + k) * 512 + l * 8,      \
                           smem + (buf) * 12288 + 4096 + (w * 4 + k) * 512 + l * 8); \
        }

    f32x4 acc1[4][2];
    #pragma unroll
    for (int mt = 0; mt < 4; ++mt) {
        acc1[mt][0] = (f32x4){0.f, 0.f, 0.f, 0.f};
        acc1[mt][1] = (f32x4){0.f, 0.f, 0.f, 0.f};
    }

    STAGE1(0, 0);
    STAGE1(1, 1);

    const int sxor = (l15 & 7);
    #pragma unroll
    for (int kc = 0; kc < 8; ++kc) {
        if (kc < 7) { asm volatile("s_waitcnt vmcnt(6)" ::: "memory"); }
        else        { asm volatile("s_waitcnt vmcnt(0)" ::: "memory"); }
        __builtin_amdgcn_s_barrier();
        asm volatile("" ::: "memory");

        const int base = (kc & 1) * 12288;
        #pragma unroll
        for (int kk2 = 0; kk2 < 2; ++kk2) {
            const int cc = (kk2 * 4 + g) ^ sxor;
            short8_t af[4], bf[2];
            #pragma unroll
            for (int mt = 0; mt < 4; ++mt)
                af[mt] = *(const short8_t*)(smem + base + (16 * mt + l15) * 64 + cc * 8);
            #pragma unroll
            for (int ni = 0; ni < 2; ++ni)
                bf[ni] = *(const short8_t*)(smem + base + 4096
                                            + (32 * w + 16 * ni + l15) * 64 + cc * 8);
            #pragma unroll
            for (int mt = 0; mt < 4; ++mt)
                #pragma unroll
                for (int ni = 0; ni < 2; ++ni)
                    acc1[mt][ni] = __builtin_amdgcn_mfma_f32_16x16x32_bf16(
                        af[mt], bf[ni], acc1[mt][ni], 0, 0, 0);
        }

        asm volatile("" ::: "memory");
        __builtin_amdgcn_s_barrier();
        if (kc < 6) STAGE1(kc + 2, kc & 1);
    }
    #undef STAGE1

    // bias + relu -> h1s [64][136] (bank-staggered)
    unsigned short* h1s = smem;
    #pragma unroll
    for (int ni = 0; ni < 2; ++ni) {
        const int i = 32 * w + 16 * ni + l15;
        const float b1v = b1[c * H1_ + i];
        #pragma unroll
        for (int mt = 0; mt < 4; ++mt)
            #pragma unroll
            for (int r = 0; r < 4; ++r) {
                float h = acc1[mt][ni][r] + b1v;
                h = h > 0.f ? h : 0.f;
                h1s[(16 * mt + 4 * g + r) * 136 + i] = f2bf(h);
            }
    }
    __syncthreads();

    // fragment-major writeout: unit u -> frag f = u>>6 (mt=f>>2, kk=f&3),
    // lane ll = u&63: src (t = 16mt + ll&15, i = 32kk + 8*(ll>>4)).
    unsigned short* dst = h1g + (size_t)(b * 12 + pq) * 8192;
    #pragma unroll
    for (int it = 0; it < 4; ++it) {
        int u = tid + it * 256;            // 0..1023
        int f = u >> 6, ll = u & 63;
        int t = (f >> 2) * 16 + (ll & 15);
        int i = (f & 3) * 32 + (ll >> 4) * 8;
        short8_t v = *(const short8_t*)&h1s[t * 136 + i];
        *(short8_t*)(dst + f * 512 + ll * 8) = v;
    }
}

// ---------------------------------------------------------------------------
// Kernel B (phase 2+3), v15: SWAPPED MFMA operands — mfma(W2frag, h1frag)
// gives D[o][t] with col=t=16mt+l15, row=o=16nt+4g+r. Layer-3 o-reduction
// becomes: 4 in-register r-FMAs (fused into s-update) + 2 shfl_xor per mt.
// Sigmoid + store: lane l owns t=l (one value per rs) — full-wave parallel.
// NO LDS, NO barriers; all loads 1KB-coalesced fragment-major.
// ---------------------------------------------------------------------------
__global__ __launch_bounds__(256) void fused_p2(
    const unsigned short* __restrict__ h1g, const unsigned short* __restrict__ W2f,
    const int* __restrict__ cam, const int* __restrict__ ord,
    const float* __restrict__ b2, const float* __restrict__ W3,
    const float* __restrict__ b3, float* __restrict__ out)
{
    const int idx = blockIdx.x;
    const int swz = (idx & 7) * 192 + (idx >> 3);   // same swizzle as A
    const int bpos = swz / 12, pq = swz - bpos * 12;
    const int b = ord[bpos];

    const int tid = threadIdx.x;
    const int w = tid >> 6, l = tid & 63;
    const int g = l >> 4;
    const int c = cam[b];

    // a2 fragments (B-operand: row t=l15, k=i): 16 coalesced 1KB wave loads
    const unsigned short* h1f = h1g + (size_t)(b * 12 + pq) * 8192;
    short8_t a2[4][4];
    #pragma unroll
    for (int mt = 0; mt < 4; ++mt)
        #pragma unroll
        for (int kk = 0; kk < 4; ++kk)
            a2[mt][kk] = *(const short8_t*)(h1f + (mt * 4 + kk) * 512 + l * 8);

    // W2 fragment tiles (A-operand: row o=l15, k=i)
    const unsigned short* W2base = W2f + (size_t)(c * 12 + w * 3) * 8192;

    short8_t bfr[2][4];
    #pragma unroll
    for (int kk = 0; kk < 4; ++kk)
        bfr[0][kk] = *(const short8_t*)(W2base + kk * 512 + l * 8);   // seg0: nt=0

    // per-lane epilogue constants: o = 16*nt + 4*g + r
    float w3v[4][4], b2v[4][4];
    #pragma unroll
    for (int nt = 0; nt < 4; ++nt)
        #pragma unroll
        for (int r = 0; r < 4; ++r) {
            w3v[nt][r] = W3[c * H2_ + nt * 16 + g * 4 + r];
            b2v[nt][r] = b2[c * H2_ + nt * 16 + g * 4 + r];
        }
    const float b3v = b3[c];
    const int p = pq >> 2, q = pq & 3;

    float s[4] = {0.f, 0.f, 0.f, 0.f};

    // seg = 0..11 : rs_local = seg>>2, nt = seg&3 ; 1-ahead 2-slot prefetch
    #pragma unroll
    for (int seg = 0; seg < 12; ++seg) {
        if (seg < 11) {
            const int ns = seg + 1;
            const unsigned short* nb = W2base + (ns >> 2) * 8192 + ((ns & 3) * 4) * 512;
            #pragma unroll
            for (int kk = 0; kk < 4; ++kk)
                bfr[(seg + 1) & 1][kk] = *(const short8_t*)(nb + kk * 512 + l * 8);
        }
        const int nt = seg & 3;
        #pragma unroll
        for (int mt = 0; mt < 4; ++mt) {
            f32x4 acc2 = (f32x4){0.f, 0.f, 0.f, 0.f};
            #pragma unroll
            for (int kk = 0; kk < 4; ++kk)
                acc2 = __builtin_amdgcn_mfma_f32_16x16x32_bf16(
                    bfr[seg & 1][kk], a2[mt][kk], acc2, 0, 0, 0);
            #pragma unroll
            for (int r = 0; r < 4; ++r)
                s[mt] = fmaf(w3v[nt][r], fmaxf(acc2[r] + b2v[nt][r], 0.f), s[mt]);
        }

        if (nt == 3) {
            const int rs = w * 3 + (seg >> 2);
            const int hrow = p * 3 + (rs >> 2), wcol = q * 4 + (rs & 3);
            // reduce over g (o-groups): lanes xor 16, 32
            #pragma unroll
            for (int mt = 0; mt < 4; ++mt) {
                s[mt] += __shfl_xor(s[mt], 16);
                s[mt] += __shfl_xor(s[mt], 32);
            }
            // lane l owns t = l  (t = 16*g + l15), pick s[g] statically
            float v = (g & 1) ? ((g & 2) ? s[3] : s[1]) : ((g & 2) ? s[2] : s[0]);
            v += b3v;
            if (l < T_)
                out[(((size_t)b * T_ + l) * 9 + hrow) * 16 + wcol] =
                    1.f / (1.f + __expf(-v));
            s[0] = s[1] = s[2] = s[3] = 0.f;
        }
    }
}

// ---------------------------------------------------------------------------
// fp32 VALU fallback — used only if ws too small
// ---------------------------------------------------------------------------
__global__ __launch_bounds__(256) void fused_decoder_f32(
    const float* __restrict__ x,   const int* __restrict__ cam,
    const float* __restrict__ W1,  const float* __restrict__ b1,
    const float* __restrict__ W2,  const float* __restrict__ b2,
    const float* __restrict__ W3,  const float* __restrict__ b3,
    float* __restrict__ out)
{
    __shared__ float h1s[T_ * H1_];
    __shared__ float stage[8192];

    const int pq  = blockIdx.x;
    const int b   = blockIdx.y;
    const int p   = pq >> 2, q = pq & 3;
    const int tid = threadIdx.x;
    const int c   = cam[b];

    float* xs  = stage;
    float* w1s = stage + 2048;

    const int ig = tid & 31;
    const int tg = tid >> 5;

    float acc[8][4];
    #pragma unroll
    for (int a = 0; a < 8; ++a)
        #pragma unroll
        for (int j = 0; j < 4; ++j) acc[a][j] = 0.f;

    for (int f0 = 0; f0 < F_; f0 += 32) {
        __syncthreads();
        {
            int lane = tid & 63;
            int sub  = tid >> 6;
            if (lane < T_) {
                #pragma unroll
                for (int m = 0; m < 8; ++m) {
                    int kk = sub * 8 + m;
                    xs[kk * 64 + lane] = x[((size_t)b * F_ + f0 + kk) * T_ + lane];
                }
            }
        }
        for (int e = tid; e < 32 * H1_; e += 256) {
            int kk = e >> 7, i = e & 127;
            w1s[e] = W1[(((size_t)c * F_ + f0 + kk) * H1_ + i) * 12 + pq];
        }
        __syncthreads();
        #pragma unroll 8
        for (int kk = 0; kk < 32; ++kk) {
            float4 bv = *(const float4*)&w1s[kk * 128 + ig * 4];
            float4 a0 = *(const float4*)&xs[kk * 64 + tg * 8];
            float4 a1 = *(const float4*)&xs[kk * 64 + tg * 8 + 4];
            float at[8] = {a0.x, a0.y, a0.z, a0.w, a1.x, a1.y, a1.z, a1.w};
            #pragma unroll
            for (int tt = 0; tt < 8; ++tt) {
                acc[tt][0] = fmaf(at[tt], bv.x, acc[tt][0]);
                acc[tt][1] = fmaf(at[tt], bv.y, acc[tt][1]);
                acc[tt][2] = fmaf(at[tt], bv.z, acc[tt][2]);
                acc[tt][3] = fmaf(at[tt], bv.w, acc[tt][3]);
            }
        }
    }
    {
        float4 b1v = *(const float4*)&b1[c * H1_ + ig * 4];
        #pragma unroll
        for (int tt = 0; tt < 8; ++tt) {
            int t = tg * 8 + tt;
            if (t < T_) {
                float4 hv;
                hv.x = fmaxf(acc[tt][0] + b1v.x, 0.f);
                hv.y = fmaxf(acc[tt][1] + b1v.y, 0.f);
                hv.z = fmaxf(acc[tt][2] + b1v.z, 0.f);
                hv.w = fmaxf(acc[tt][3] + b1v.w, 0.f);
                *(float4*)&h1s[t * H1_ + ig * 4] = hv;
            }
        }
    }

    const int lane = tid & 63;
    const int wv   = tid >> 6;
    const float w3v = W3[c * H2_ + lane];
    const float b2v = b2[c * H2_ + lane];
    const float b3v = b3[c];
    float* w2s = stage;

    for (int rs = 0; rs < 12; ++rs) {
        __syncthreads();
        for (int e = tid; e < H1_ * H2_; e += 256) {
            int i = e >> 6, o = e & 63;
            w2s[e] = W2[(((size_t)c * H1_ + i) * H2_ + o) * 12 + rs];
        }
        __syncthreads();

        float acc2[15];
        #pragma unroll
        for (int j = 0; j < 15; ++j) acc2[j] = 0.f;

        for (int i = 0; i < H1_; i += 4) {
            float wa = w2s[(i + 0) * 64 + lane];
            float wb = w2s[(i + 1) * 64 + lane];
            float wc = w2s[(i + 2) * 64 + lane];
            float wd = w2s[(i + 3) * 64 + lane];
            #pragma unroll
            for (int j = 0; j < 15; ++j) {
                float4 h = *(const float4*)&h1s[(wv * 15 + j) * H1_ + i];
                acc2[j] = fmaf(h.x, wa, acc2[j]);
                acc2[j] = fmaf(h.y, wb, acc2[j]);
                acc2[j] = fmaf(h.z, wc, acc2[j]);
                acc2[j] = fmaf(h.w, wd, acc2[j]);
            }
        }

        const int r = rs >> 2, s = rs & 3;
        const int hrow = p * 3 + r, wcol = q * 4 + s;
        #pragma unroll
        for (int j = 0; j < 15; ++j) {
            float y = w3v * fmaxf(acc2[j] + b2v, 0.f);
            #pragma unroll
            for (int m = 32; m > 0; m >>= 1) y += __shfl_xor(y, m, 64);
            if (lane == j) {
                int t = wv * 15 + j;
                float v = y + b3v;
                out[(((size_t)b * T_ + t) * 9 + hrow) * 16 + wcol] = 1.f / (1.f + __expf(-v));
            }
        }
    }
}

// ---------------------------------------------------------------------------
extern "C" void kernel_launch(void* const* d_in, const int* in_sizes, int n_in,
                              void* d_out, int out_size, void* d_ws, size_t ws_size,
                              hipStream_t stream) {
    const float* x   = (const float*)d_in[0];
    const int*   cam = (const int*)  d_in[1];
    const float* W1  = (const float*)d_in[2];
    const float* b1  = (const float*)d_in[3];
    const float* W2  = (const float*)d_in[4];
    const float* b2  = (const float*)d_in[5];
    const float* W3  = (const float*)d_in[6];
    const float* b3  = (const float*)d_in[7];
    float* outp = (float*)d_out;

    const size_t n_xT  = (size_t)B_ * 32768;            //  4,194,304 (swizzled A images)
    const size_t n_w1s = (size_t)C_ * 12 * 65536;       // 11,796,480 (swizzled B images)
    const size_t n_w2f = (size_t)C_ * 12 * 16 * 512;    //  1,474,560 (fragment-major)
    const size_t n_h1  = (size_t)B_ * 12 * 8192;        // 12,582,912 (fragment-major tiles)
    const size_t needed = (n_xT + n_w1s + n_w2f + n_h1) * sizeof(unsigned short)
                        + B_ * sizeof(int);

    if (d_ws != nullptr && ws_size >= needed) {
        unsigned short* xTs = (unsigned short*)d_ws;
        unsigned short* W1p = xTs + n_xT;
        unsigned short* W2p = W1p + n_w1s;
        unsigned short* h1g = W2p + n_w2f;
        int* ord = (int*)(h1g + n_h1);
        make_order<<<1, 128, 0, stream>>>(cam, ord);
        repack_x <<<dim3(4, B_), 256, 0, stream>>>(x, xTs);
        repack_w1<<<dim3(F_ / 32, H1_ / 32, C_), 256, 0, stream>>>(W1, W1p);
        repack_w2<<<dim3(H1_ / 32, H2_ / 32, C_), 256, 0, stream>>>(W2, W2p);
        fused_p1<<<dim3(12 * B_), 256, 0, stream>>>(xTs, W1p, cam, ord, b1, h1g);
        fused_p2<<<dim3(12 * B_), 256, 0, stream>>>(h1g, W2p, cam, ord, b2, W3, b3, outp);
    } else {
        fused_decoder_f32<<<dim3(12, B_), 256, 0, stream>>>(
            x, cam, W1, b1, W2, b2, W3, b3, outp);
    }
}

// Round 16
// 62.750 us; speedup vs baseline: 1.8186x; 1.2257x over previous
//
#include <hip/hip_runtime.h>
#include <hip/hip_bf16.h>
#include <cstdint>

// Problem constants
#define B_  128
#define F_  512
#define T_  60
#define C_  15
#define H1_ 128
#define H2_ 64

typedef short short8_t __attribute__((ext_vector_type(8)));   // 8 bf16 (4 VGPR)
typedef float f32x4    __attribute__((ext_vector_type(4)));   // MFMA acc

static __device__ __forceinline__ unsigned short f2bf(float f) {
    union { float f; uint32_t u; } v; v.f = f;
    uint32_t r = v.u + 0x7FFF + ((v.u >> 16) & 1);   // RNE
    return (unsigned short)(r >> 16);
}

// async 16B global -> LDS DMA (dest = wave-uniform base + lane*16)
static __device__ __forceinline__ void async_cp16(const unsigned short* g, unsigned short* l) {
    __builtin_amdgcn_global_load_lds(
        (const __attribute__((address_space(1))) unsigned int*)g,
        (__attribute__((address_space(3))) unsigned int*)l, 16, 0, 0);
}

// ---------------------------------------------------------------------------
// prep_misc: one launch for {repack_x (blocks 0..511), repack_w2 (512..631),
// make_order (632)}. 48KB LDS unioned across branches.
//  repack_x : x (B,F,T) f32 -> xTs (B, 8 kc, swizzled 64x64 image) bf16,
//             unit (kc,t,cc): k = kc*64 + (cc^(t&7))*8 .. +8
//  repack_w2: W2 (C,H1,H2,3,4) f32 -> W2f fragment-major (tile=16 frag x 512:
//             frag nt*4+kk, lane l: o=16nt+(l&15), i=32kk+8*(l>>4)..+8)
//  make_order: ord[rank]=b, stable camera sort.
// ---------------------------------------------------------------------------
__global__ __launch_bounds__(256) void prep_misc(
    const float* __restrict__ x, const float* __restrict__ W2,
    const int* __restrict__ cam,
    unsigned short* __restrict__ xTs, unsigned short* __restrict__ W2f,
    int* __restrict__ ord)
{
    __shared__ float sm[12288];   // 48 KB
    const int blk = blockIdx.x, tid = threadIdx.x;

    if (blk < 512) {
        // ---------------- repack_x ----------------
        float (*xs)[61] = (float(*)[61])sm;          // 128 x 61 floats
        const int f0 = (blk & 3) * 128, b = blk >> 2;
        #pragma unroll
        for (int it = 0; it < 32; ++it) {
            int idx = tid + it * 256;                // 128*64
            int fl = idx >> 6, t = idx & 63;
            if (t < T_) xs[fl][t] = x[((size_t)b * F_ + f0 + fl) * T_ + t];
        }
        __syncthreads();
        #pragma unroll
        for (int it = 0; it < 8; ++it) {
            int idx = tid + it * 256;                // 64*32
            int t = idx >> 5, f4 = (idx & 31) * 4;
            ushort4 o;
            o.x = (t < T_) ? f2bf(xs[f4 + 0][t]) : 0;
            o.y = (t < T_) ? f2bf(xs[f4 + 1][t]) : 0;
            o.z = (t < T_) ? f2bf(xs[f4 + 2][t]) : 0;
            o.w = (t < T_) ? f2bf(xs[f4 + 3][t]) : 0;
            const int f = f0 + f4;
            const int kc = f >> 6, within = f & 63;
            const int cc = (within >> 3) ^ (t & 7), half = (within >> 2) & 1;
            *(ushort4*)(xTs + (size_t)b * 32768 + kc * 4096 + t * 64 + cc * 8 + half * 4) = o;
        }
    } else if (blk < 632) {
        // ---------------- repack_w2 ----------------
        float (*ls)[384] = (float(*)[384])sm;        // 32 x 384 floats (48KB)
        const int id = blk - 512;                    // 0..119
        const int i0 = (id & 3) * 32, o0 = ((id >> 2) & 1) * 32, c = id >> 3;
        #pragma unroll
        for (int it = 0; it < 12; ++it) {
            int idx = tid + it * 256;
            int il = idx / 96, r = idx - il * 96;
            float4 v = *(const float4*)(W2 + ((size_t)(c * H1_ + i0 + il)) * (H2_ * 12)
                                           + (size_t)o0 * 12 + r * 4);
            *(float4*)&ls[il][r * 4] = v;
        }
        __syncthreads();
        const int o_l = tid >> 3, i_l = (tid & 7) * 4;
        const int o  = o0 + o_l;
        const int nt = o >> 4, l15 = o & 15;
        const int lane = l15 + 16 * ((i_l >> 3) & 3);
        const int kk  = i0 >> 5;
        const int pos = i_l & 7;
        #pragma unroll
        for (int rs = 0; rs < 12; ++rs) {
            ushort4 v;
            v.x = f2bf(ls[i_l + 0][o_l * 12 + rs]);
            v.y = f2bf(ls[i_l + 1][o_l * 12 + rs]);
            v.z = f2bf(ls[i_l + 2][o_l * 12 + rs]);
            v.w = f2bf(ls[i_l + 3][o_l * 12 + rs]);
            *(ushort4*)(W2f + ((size_t)(c * 12 + rs) * 16 + nt * 4 + kk) * 512
                            + lane * 8 + pos) = v;
        }
    } else {
        // ---------------- make_order ----------------
        int* cs = (int*)sm;
        if (tid < B_) cs[tid] = cam[tid];
        __syncthreads();
        if (tid < B_) {
            const int cb = cs[tid];
            int rank = 0;
            #pragma unroll 16
            for (int j = 0; j < B_; ++j) {
                int cj = cs[j];
                rank += (cj < cb || (cj == cb && j < tid)) ? 1 : 0;
            }
            ord[rank] = tid;
        }
    }
}

// ---------------------------------------------------------------------------
// Repack W1 (C,F,H1,3,4) f32 -> W1s[(c*12+pq)][kc][swizzled 128x64 image] bf16
//   slice = 65536 ush; kc chunk = 8192 ush; unit k = kc*64 + (cc^(i&7))*8..+8
// ---------------------------------------------------------------------------
__global__ __launch_bounds__(256) void repack_w1(const float* __restrict__ W1,
                                                 unsigned short* __restrict__ W1s) {
    __shared__ float ls[32][384];
    const int f0 = blockIdx.x * 32, i0 = blockIdx.y * 32, c = blockIdx.z;
    const int tid = threadIdx.x;
    #pragma unroll
    for (int it = 0; it < 12; ++it) {
        int idx = tid + it * 256;              // 3072 float4
        int fl = idx / 96, r = idx - fl * 96;
        float4 v = *(const float4*)(W1 + ((size_t)(c * F_ + f0 + fl)) * (H1_ * 12)
                                       + (size_t)i0 * 12 + r * 4);
        *(float4*)&ls[fl][r * 4] = v;
    }
    __syncthreads();
    const int i_l = tid >> 3, f_l = (tid & 7) * 4;
    const int i = i0 + i_l, f = f0 + f_l;
    const int kc = f >> 6, within = f & 63;
    const int cc = (within >> 3) ^ (i & 7), half = (within >> 2) & 1;
    #pragma unroll
    for (int pq = 0; pq < 12; ++pq) {
        ushort4 o;
        o.x = f2bf(ls[f_l + 0][i_l * 12 + pq]);
        o.y = f2bf(ls[f_l + 1][i_l * 12 + pq]);
        o.z = f2bf(ls[f_l + 2][i_l * 12 + pq]);
        o.w = f2bf(ls[f_l + 3][i_l * 12 + pq]);
        *(ushort4*)(W1s + (size_t)(c * 12 + pq) * 65536
                        + kc * 8192 + i * 64 + cc * 8 + half * 4) = o;
    }
}

// ---------------------------------------------------------------------------
// Fused decoder v16 = p1 (R10 staging loop) + SWAPPED phase2 (R15) reading
// h1 B-fragments straight from LDS — no h1 global round-trip.
// Phase1: LDS double-buffer, counted vmcnt, raw barriers, XOR-swizzle images.
// Phase2: mfma(W2frag, h1frag) -> D[o][t] (col=t=16mt+l15, row=o=16nt+4g+r);
//   layer-3 o-reduce = 4 in-reg r-FMAs + 2 shfl_xor; lane l owns t=l.
//   W2 prefetch + w3/b2 loads issued BEFORE the h1s barrier (T14).
// ---------------------------------------------------------------------------
__global__ __launch_bounds__(256) void fused_all(
    const unsigned short* __restrict__ xTs, const unsigned short* __restrict__ W1s,
    const unsigned short* __restrict__ W2f, const int* __restrict__ cam,
    const int* __restrict__ ord,
    const float* __restrict__ b1, const float* __restrict__ b2,
    const float* __restrict__ W3, const float* __restrict__ b3,
    float* __restrict__ out)
{
    __shared__ __align__(16) unsigned short smem[24576];   // 48 KB

    const int idx = blockIdx.x;
    const int swz = (idx & 7) * 192 + (idx >> 3);   // bijective XCD swizzle
    const int bpos = swz / 12, pq = swz - bpos * 12;
    const int b = ord[bpos];

    const int tid = threadIdx.x;
    const int w = tid >> 6, l = tid & 63;
    const int l15 = l & 15, g = l >> 4;
    const int c = cam[b];

    // ---------------- Phase 1: h1(64x128) = xT(64x512) * W1^T ----------------
    const unsigned short* xchunk = xTs + (size_t)b * 32768;             // 8 x 4096
    const unsigned short* wchunk = W1s + (size_t)(c * 12 + pq) * 65536; // 8 x 8192

    #define STAGE1(kc, buf)                                                       \
        {                                                                         \
            _Pragma("unroll")                                                     \
            for (int k = 0; k < 2; ++k)                                           \
                async_cp16(xchunk + (kc) * 4096 + (w * 2 + k) * 512 + l * 8,      \
                           smem + (buf) * 12288 + (w * 2 + k) * 512 + l * 8);     \
            _Pragma("unroll")                                                     \
            for (int k = 0; k < 4; ++k)                                           \
                async_cp16(wchunk + (kc) * 8192 + (w * 4 + k) * 512 + l * 8,      \
                           smem + (buf) * 12288 + 4096 + (w * 4 + k) * 512 + l * 8); \
        }

    f32x4 acc1[4][2];
    #pragma unroll
    for (int mt = 0; mt < 4; ++mt) {
        acc1[mt][0] = (f32x4){0.f, 0.f, 0.f, 0.f};
        acc1[mt][1] = (f32x4){0.f, 0.f, 0.f, 0.f};
    }

    STAGE1(0, 0);
    STAGE1(1, 1);

    const int sxor = (l15 & 7);
    #pragma unroll
    for (int kc = 0; kc < 8; ++kc) {
        if (kc < 7) { asm volatile("s_waitcnt vmcnt(6)" ::: "memory"); }
        else        { asm volatile("s_waitcnt vmcnt(0)" ::: "memory"); }
        __builtin_amdgcn_s_barrier();
        asm volatile("" ::: "memory");

        const int base = (kc & 1) * 12288;
        #pragma unroll
        for (int kk2 = 0; kk2 < 2; ++kk2) {
            const int cc = (kk2 * 4 + g) ^ sxor;
            short8_t af[4], bf[2];
            #pragma unroll
            for (int mt = 0; mt < 4; ++mt)
                af[mt] = *(const short8_t*)(smem + base + (16 * mt + l15) * 64 + cc * 8);
            #pragma unroll
            for (int ni = 0; ni < 2; ++ni)
                bf[ni] = *(const short8_t*)(smem + base + 4096
                                            + (32 * w + 16 * ni + l15) * 64 + cc * 8);
            #pragma unroll
            for (int mt = 0; mt < 4; ++mt)
                #pragma unroll
                for (int ni = 0; ni < 2; ++ni)
                    acc1[mt][ni] = __builtin_amdgcn_mfma_f32_16x16x32_bf16(
                        af[mt], bf[ni], acc1[mt][ni], 0, 0, 0);
        }

        asm volatile("" ::: "memory");
        __builtin_amdgcn_s_barrier();
        if (kc < 6) STAGE1(kc + 2, kc & 1);
    }
    #undef STAGE1

    // ---- phase-2 prefetches issued before the h1s barrier (T14) ----
    const unsigned short* W2base = W2f + (size_t)(c * 12 + w * 3) * 8192;
    short8_t bfr[2][4];
    #pragma unroll
    for (int kk = 0; kk < 4; ++kk)
        bfr[0][kk] = *(const short8_t*)(W2base + kk * 512 + l * 8);   // seg0: nt=0

    float w3v[4][4], b2v[4][4];
    #pragma unroll
    for (int nt = 0; nt < 4; ++nt)
        #pragma unroll
        for (int r = 0; r < 4; ++r) {
            w3v[nt][r] = W3[c * H2_ + nt * 16 + g * 4 + r];
            b2v[nt][r] = b2[c * H2_ + nt * 16 + g * 4 + r];
        }
    const float b3v = b3[c];
    const int p = pq >> 2, q = pq & 3;

    // bias + relu -> h1s [64][136] (bank-staggered)
    unsigned short* h1s = smem;
    #pragma unroll
    for (int ni = 0; ni < 2; ++ni) {
        const int i = 32 * w + 16 * ni + l15;
        const float b1v = b1[c * H1_ + i];
        #pragma unroll
        for (int mt = 0; mt < 4; ++mt)
            #pragma unroll
            for (int r = 0; r < 4; ++r) {
                float h = acc1[mt][ni][r] + b1v;
                h = h > 0.f ? h : 0.f;
                h1s[(16 * mt + 4 * g + r) * 136 + i] = f2bf(h);
            }
    }
    __syncthreads();

    // ---------------- Phase 2 (swapped operands) ----------------
    // a2 = h1 B-fragments: row t = 16mt + l15, k = i = 32kk + 8g .. +8
    short8_t a2[4][4];
    #pragma unroll
    for (int mt = 0; mt < 4; ++mt)
        #pragma unroll
        for (int kk = 0; kk < 4; ++kk)
            a2[mt][kk] = *(const short8_t*)&h1s[(16 * mt + l15) * 136 + 32 * kk + 8 * g];

    float s[4] = {0.f, 0.f, 0.f, 0.f};

    // seg = 0..11 : rs_local = seg>>2, nt = seg&3 ; 1-ahead 2-slot prefetch
    #pragma unroll
    for (int seg = 0; seg < 12; ++seg) {
        if (seg < 11) {
            const int ns = seg + 1;
            const unsigned short* nb = W2base + (ns >> 2) * 8192 + ((ns & 3) * 4) * 512;
            #pragma unroll
            for (int kk = 0; kk < 4; ++kk)
                bfr[(seg + 1) & 1][kk] = *(const short8_t*)(nb + kk * 512 + l * 8);
        }
        const int nt = seg & 3;
        #pragma unroll
        for (int mt = 0; mt < 4; ++mt) {
            f32x4 acc2 = (f32x4){0.f, 0.f, 0.f, 0.f};
            #pragma unroll
            for (int kk = 0; kk < 4; ++kk)
                acc2 = __builtin_amdgcn_mfma_f32_16x16x32_bf16(
                    bfr[seg & 1][kk], a2[mt][kk], acc2, 0, 0, 0);
            #pragma unroll
            for (int r = 0; r < 4; ++r)
                s[mt] = fmaf(w3v[nt][r], fmaxf(acc2[r] + b2v[nt][r], 0.f), s[mt]);
        }

        if (nt == 3) {
            const int rs = w * 3 + (seg >> 2);
            const int hrow = p * 3 + (rs >> 2), wcol = q * 4 + (rs & 3);
            #pragma unroll
            for (int mt = 0; mt < 4; ++mt) {
                s[mt] += __shfl_xor(s[mt], 16);
                s[mt] += __shfl_xor(s[mt], 32);
            }
            float v = (g & 1) ? ((g & 2) ? s[3] : s[1]) : ((g & 2) ? s[2] : s[0]);
            v += b3v;
            if (l < T_)
                out[(((size_t)b * T_ + l) * 9 + hrow) * 16 + wcol] =
                    1.f / (1.f + __expf(-v));
            s[0] = s[1] = s[2] = s[3] = 0.f;
        }
    }
}

// ---------------------------------------------------------------------------
// fp32 VALU fallback — used only if ws too small
// ---------------------------------------------------------------------------
__global__ __launch_bounds__(256) void fused_decoder_f32(
    const float* __restrict__ x,   const int* __restrict__ cam,
    const float* __restrict__ W1,  const float* __restrict__ b1,
    const float* __restrict__ W2,  const float* __restrict__ b2,
    const float* __restrict__ W3,  const float* __restrict__ b3,
    float* __restrict__ out)
{
    __shared__ float h1s[T_ * H1_];
    __shared__ float stage[8192];

    const int pq  = blockIdx.x;
    const int b   = blockIdx.y;
    const int p   = pq >> 2, q = pq & 3;
    const int tid = threadIdx.x;
    const int c   = cam[b];

    float* xs  = stage;
    float* w1s = stage + 2048;

    const int ig = tid & 31;
    const int tg = tid >> 5;

    float acc[8][4];
    #pragma unroll
    for (int a = 0; a < 8; ++a)
        #pragma unroll
        for (int j = 0; j < 4; ++j) acc[a][j] = 0.f;

    for (int f0 = 0; f0 < F_; f0 += 32) {
        __syncthreads();
        {
            int lane = tid & 63;
            int sub  = tid >> 6;
            if (lane < T_) {
                #pragma unroll
                for (int m = 0; m < 8; ++m) {
                    int kk = sub * 8 + m;
                    xs[kk * 64 + lane] = x[((size_t)b * F_ + f0 + kk) * T_ + lane];
                }
            }
        }
        for (int e = tid; e < 32 * H1_; e += 256) {
            int kk = e >> 7, i = e & 127;
            w1s[e] = W1[(((size_t)c * F_ + f0 + kk) * H1_ + i) * 12 + pq];
        }
        __syncthreads();
        #pragma unroll 8
        for (int kk = 0; kk < 32; ++kk) {
            float4 bv = *(const float4*)&w1s[kk * 128 + ig * 4];
            float4 a0 = *(const float4*)&xs[kk * 64 + tg * 8];
            float4 a1 = *(const float4*)&xs[kk * 64 + tg * 8 + 4];
            float at[8] = {a0.x, a0.y, a0.z, a0.w, a1.x, a1.y, a1.z, a1.w};
            #pragma unroll
            for (int tt = 0; tt < 8; ++tt) {
                acc[tt][0] = fmaf(at[tt], bv.x, acc[tt][0]);
                acc[tt][1] = fmaf(at[tt], bv.y, acc[tt][1]);
                acc[tt][2] = fmaf(at[tt], bv.z, acc[tt][2]);
                acc[tt][3] = fmaf(at[tt], bv.w, acc[tt][3]);
            }
        }
    }
    {
        float4 b1v = *(const float4*)&b1[c * H1_ + ig * 4];
        #pragma unroll
        for (int tt = 0; tt < 8; ++tt) {
            int t = tg * 8 + tt;
            if (t < T_) {
                float4 hv;
                hv.x = fmaxf(acc[tt][0] + b1v.x, 0.f);
                hv.y = fmaxf(acc[tt][1] + b1v.y, 0.f);
                hv.z = fmaxf(acc[tt][2] + b1v.z, 0.f);
                hv.w = fmaxf(acc[tt][3] + b1v.w, 0.f);
                *(float4*)&h1s[t * H1_ + ig * 4] = hv;
            }
        }
    }

    const int lane = tid & 63;
    const int wv   = tid >> 6;
    const float w3v = W3[c * H2_ + lane];
    const float b2v = b2[c * H2_ + lane];
    const float b3v = b3[c];
    float* w2s = stage;

    for (int rs = 0; rs < 12; ++rs) {
        __syncthreads();
        for (int e = tid; e < H1_ * H2_; e += 256) {
            int i = e >> 6, o = e & 63;
            w2s[e] = W2[(((size_t)c * H1_ + i) * H2_ + o) * 12 + rs];
        }
        __syncthreads();

        float acc2[15];
        #pragma unroll
        for (int j = 0; j < 15; ++j) acc2[j] = 0.f;

        for (int i = 0; i < H1_; i += 4) {
            float wa = w2s[(i + 0) * 64 + lane];
            float wb = w2s[(i + 1) * 64 + lane];
            float wc = w2s[(i + 2) * 64 + lane];
            float wd = w2s[(i + 3) * 64 + lane];
            #pragma unroll
            for (int j = 0; j < 15; ++j) {
                float4 h = *(const float4*)&h1s[(wv * 15 + j) * H1_ + i];
                acc2[j] = fmaf(h.x, wa, acc2[j]);
                acc2[j] = fmaf(h.y, wb, acc2[j]);
                acc2[j] = fmaf(h.z, wc, acc2[j]);
                acc2[j] = fmaf(h.w, wd, acc2[j]);
            }
        }

        const int r = rs >> 2, s = rs & 3;
        const int hrow = p * 3 + r, wcol = q * 4 + s;
        #pragma unroll
        for (int j = 0; j < 15; ++j) {
            float y = w3v * fmaxf(acc2[j] + b2v, 0.f);
            #pragma unroll
            for (int m = 32; m > 0; m >>= 1) y += __shfl_xor(y, m, 64);
            if (lane == j) {
                int t = wv * 15 + j;
                float v = y + b3v;
                out[(((size_t)b * T_ + t) * 9 + hrow) * 16 + wcol] = 1.f / (1.f + __expf(-v));
            }
        }
    }
}

// ---------------------------------------------------------------------------
extern "C" void kernel_launch(void* const* d_in, const int* in_sizes, int n_in,
                              void* d_out, int out_size, void* d_ws, size_t ws_size,
                              hipStream_t stream) {
    const float* x   = (const float*)d_in[0];
    const int*   cam = (const int*)  d_in[1];
    const float* W1  = (const float*)d_in[2];
    const float* b1  = (const float*)d_in[3];
    const float* W2  = (const float*)d_in[4];
    const float* b2  = (const float*)d_in[5];
    const float* W3  = (const float*)d_in[6];
    const float* b3  = (const float*)d_in[7];
    float* outp = (float*)d_out;

    const size_t n_xT  = (size_t)B_ * 32768;            //  4,194,304 (swizzled A images)
    const size_t n_w1s = (size_t)C_ * 12 * 65536;       // 11,796,480 (swizzled B images)
    const size_t n_w2f = (size_t)C_ * 12 * 16 * 512;    //  1,474,560 (fragment-major)
    const size_t needed = (n_xT + n_w1s + n_w2f) * sizeof(unsigned short)
                        + B_ * sizeof(int);

    if (d_ws != nullptr && ws_size >= needed) {
        unsigned short* xTs = (unsigned short*)d_ws;
        unsigned short* W1p = xTs + n_xT;
        unsigned short* W2p = W1p + n_w1s;
        int* ord = (int*)(W2p + n_w2f);
        prep_misc<<<633, 256, 0, stream>>>(x, W2, cam, xTs, W2p, ord);
        repack_w1<<<dim3(F_ / 32, H1_ / 32, C_), 256, 0, stream>>>(W1, W1p);
        fused_all<<<dim3(12 * B_), 256, 0, stream>>>(
            xTs, W1p, W2p, cam, ord, b1, b2, W3, b3, outp);
    } else {
        fused_decoder_f32<<<dim3(12, B_), 256, 0, stream>>>(
            x, cam, W1, b1, W2, b2, W3, b3, outp);
    }
}

// Round 17
// 60.835 us; speedup vs baseline: 1.8759x; 1.0315x over previous
//
#include <hip/hip_runtime.h>
#include <hip/hip_bf16.h>
#include <cstdint>

// Problem constants
#define B_  128
#define F_  512
#define T_  60
#define C_  15
#define H1_ 128
#define H2_ 64

typedef short short8_t __attribute__((ext_vector_type(8)));   // 8 bf16 (4 VGPR)
typedef float f32x4    __attribute__((ext_vector_type(4)));   // MFMA acc

static __device__ __forceinline__ unsigned short f2bf(float f) {
    union { float f; uint32_t u; } v; v.f = f;
    uint32_t r = v.u + 0x7FFF + ((v.u >> 16) & 1);   // RNE
    return (unsigned short)(r >> 16);
}

// async 16B global -> LDS DMA (dest = wave-uniform base + lane*16)
static __device__ __forceinline__ void async_cp16(const unsigned short* g, unsigned short* l) {
    __builtin_amdgcn_global_load_lds(
        (const __attribute__((address_space(1))) unsigned int*)g,
        (__attribute__((address_space(3))) unsigned int*)l, 16, 0, 0);
}

// Image swizzle key for BK=32 rows (64B): spreads 16-lane frag reads over 8 banks
#define KEY(r) (((r) & 3) ^ (((r) >> 2) & 3))

// ---------------------------------------------------------------------------
// prep_all: ONE launch for all prep.
//   blocks 0..511   : repack_x  -> xTs (B, 16 kc, [64 t][4 cc] image) bf16
//                     unit (kc,t,cc): k_local = (cc ^ KEY(t))*8 .. +8
//   blocks 512..631 : repack_w2 -> W2f fragment-major (16 frag x 512)
//   block  632      : make_order (camera sort)
//   blocks 633..1592: repack_w1 -> W1s (c,pq): 16 kc x [128 i][4 cc] image
// ---------------------------------------------------------------------------
__global__ __launch_bounds__(256) void prep_all(
    const float* __restrict__ x, const float* __restrict__ W2,
    const float* __restrict__ W1, const int* __restrict__ cam,
    unsigned short* __restrict__ xTs, unsigned short* __restrict__ W2f,
    unsigned short* __restrict__ W1s, int* __restrict__ ord)
{
    __shared__ float sm[12288];   // 48 KB
    const int blk = blockIdx.x, tid = threadIdx.x;

    if (blk < 512) {
        // ---------------- repack_x ----------------
        float (*xs)[61] = (float(*)[61])sm;          // 128 x 61 floats
        const int f0 = (blk & 3) * 128, b = blk >> 2;
        #pragma unroll
        for (int it = 0; it < 32; ++it) {
            int idx = tid + it * 256;                // 128*64
            int fl = idx >> 6, t = idx & 63;
            if (t < T_) xs[fl][t] = x[((size_t)b * F_ + f0 + fl) * T_ + t];
        }
        __syncthreads();
        #pragma unroll
        for (int it = 0; it < 8; ++it) {
            int idx = tid + it * 256;                // 64 t x 32 f-groups
            int t = idx >> 5, f4 = (idx & 31) * 4;
            ushort4 o;
            o.x = (t < T_) ? f2bf(xs[f4 + 0][t]) : 0;
            o.y = (t < T_) ? f2bf(xs[f4 + 1][t]) : 0;
            o.z = (t < T_) ? f2bf(xs[f4 + 2][t]) : 0;
            o.w = (t < T_) ? f2bf(xs[f4 + 3][t]) : 0;
            const int f = f0 + f4;
            const int kc = f >> 5, kl = f & 31;
            const int cc = (kl >> 3) ^ KEY(t);
            *(ushort4*)(xTs + (size_t)b * 32768 + kc * 2048 + t * 32 + cc * 8 + (kl & 7)) = o;
        }
    } else if (blk < 632) {
        // ---------------- repack_w2 (fragment-major, unchanged layout) ------
        float (*ls)[384] = (float(*)[384])sm;        // 32 x 384 floats (48KB)
        const int id = blk - 512;                    // 0..119
        const int i0 = (id & 3) * 32, o0 = ((id >> 2) & 1) * 32, c = id >> 3;
        #pragma unroll
        for (int it = 0; it < 12; ++it) {
            int idx = tid + it * 256;
            int il = idx / 96, r = idx - il * 96;
            float4 v = *(const float4*)(W2 + ((size_t)(c * H1_ + i0 + il)) * (H2_ * 12)
                                           + (size_t)o0 * 12 + r * 4);
            *(float4*)&ls[il][r * 4] = v;
        }
        __syncthreads();
        const int o_l = tid >> 3, i_l = (tid & 7) * 4;
        const int o  = o0 + o_l;
        const int nt = o >> 4, l15 = o & 15;
        const int lane = l15 + 16 * ((i_l >> 3) & 3);
        const int kk  = i0 >> 5;
        const int pos = i_l & 7;
        #pragma unroll
        for (int rs = 0; rs < 12; ++rs) {
            ushort4 v;
            v.x = f2bf(ls[i_l + 0][o_l * 12 + rs]);
            v.y = f2bf(ls[i_l + 1][o_l * 12 + rs]);
            v.z = f2bf(ls[i_l + 2][o_l * 12 + rs]);
            v.w = f2bf(ls[i_l + 3][o_l * 12 + rs]);
            *(ushort4*)(W2f + ((size_t)(c * 12 + rs) * 16 + nt * 4 + kk) * 512
                            + lane * 8 + pos) = v;
        }
    } else if (blk == 632) {
        // ---------------- make_order ----------------
        int* cs = (int*)sm;
        if (tid < B_) cs[tid] = cam[tid];
        __syncthreads();
        if (tid < B_) {
            const int cb = cs[tid];
            int rank = 0;
            #pragma unroll 16
            for (int j = 0; j < B_; ++j) {
                int cj = cs[j];
                rank += (cj < cb || (cj == cb && j < tid)) ? 1 : 0;
            }
            ord[rank] = tid;
        }
    } else {
        // ---------------- repack_w1 ----------------
        float (*ls)[384] = (float(*)[384])sm;        // 32 x 384
        const int id = blk - 633;                    // 0..959
        const int f0 = (id & 15) * 32, i0 = ((id >> 4) & 3) * 32, c = id >> 6;
        #pragma unroll
        for (int it = 0; it < 12; ++it) {
            int idx = tid + it * 256;                // 3072 float4
            int fl = idx / 96, r = idx - fl * 96;
            float4 v = *(const float4*)(W1 + ((size_t)(c * F_ + f0 + fl)) * (H1_ * 12)
                                           + (size_t)i0 * 12 + r * 4);
            *(float4*)&ls[fl][r * 4] = v;
        }
        __syncthreads();
        const int i_l = tid >> 3, f_l = (tid & 7) * 4;
        const int i = i0 + i_l, f = f0 + f_l;
        const int kc = f >> 5, kl = f & 31;
        const int cc = (kl >> 3) ^ KEY(i);
        #pragma unroll
        for (int pq = 0; pq < 12; ++pq) {
            ushort4 o;
            o.x = f2bf(ls[f_l + 0][i_l * 12 + pq]);
            o.y = f2bf(ls[f_l + 1][i_l * 12 + pq]);
            o.z = f2bf(ls[f_l + 2][i_l * 12 + pq]);
            o.w = f2bf(ls[f_l + 3][i_l * 12 + pq]);
            *(ushort4*)(W1s + (size_t)(c * 12 + pq) * 65536
                            + kc * 4096 + i * 32 + cc * 8 + (kl & 7)) = o;
        }
    }
}

// ---------------------------------------------------------------------------
// Fused decoder v17: BK=32, 3-buffer staging (36 KB LDS -> 4 blocks/CU),
// stage issued 2 iterations ahead (~1200cy slack, covers HBM miss), ONE
// barrier per K-step (3-buf rotation: restage target was read a full
// iteration + barrier ago; reads are MFMA-consumed before each barrier).
// Phase2: swapped mfma(W2frag, h1frag) + cheap g-reduction (R15), unchanged.
// ---------------------------------------------------------------------------
__global__ __launch_bounds__(256) void fused_all(
    const unsigned short* __restrict__ xTs, const unsigned short* __restrict__ W1s,
    const unsigned short* __restrict__ W2f, const int* __restrict__ cam,
    const int* __restrict__ ord,
    const float* __restrict__ b1, const float* __restrict__ b2,
    const float* __restrict__ W3, const float* __restrict__ b3,
    float* __restrict__ out)
{
    // 3 bufs x (A 2048 ush + B 4096 ush) = 18432 ush = 36 KB
    __shared__ __align__(16) unsigned short smem[18432];

    const int idx = blockIdx.x;
    const int swz = (idx & 7) * 192 + (idx >> 3);   // bijective XCD swizzle
    const int bpos = swz / 12, pq = swz - bpos * 12;
    const int b = ord[bpos];

    const int tid = threadIdx.x;
    const int w = tid >> 6, l = tid & 63;
    const int l15 = l & 15, g = l >> 4;
    const int c = cam[b];

    // ---------------- Phase 1: h1(64x128) = xT(64x512) * W1^T ----------------
    const unsigned short* xchunk = xTs + (size_t)b * 32768;             // 16 x 2048
    const unsigned short* wchunk = W1s + (size_t)(c * 12 + pq) * 65536; // 16 x 4096

    // per-wave stage: 1 A cp16 (rows 16w..+15) + 2 B cp16 (rows 32w..+31) = 3 ops
    #define STAGE1(kc, buf)                                                       \
        {                                                                         \
            async_cp16(xchunk + (kc) * 2048 + w * 512 + l * 8,                    \
                       smem + (buf) * 6144 + w * 512 + l * 8);                    \
            _Pragma("unroll")                                                     \
            for (int k = 0; k < 2; ++k)                                           \
                async_cp16(wchunk + (kc) * 4096 + (w * 2 + k) * 512 + l * 8,      \
                           smem + (buf) * 6144 + 2048 + (w * 2 + k) * 512 + l * 8); \
        }

    f32x4 acc1[4][2];
    #pragma unroll
    for (int mt = 0; mt < 4; ++mt) {
        acc1[mt][0] = (f32x4){0.f, 0.f, 0.f, 0.f};
        acc1[mt][1] = (f32x4){0.f, 0.f, 0.f, 0.f};
    }

    STAGE1(0, 0);
    STAGE1(1, 1);

    const int key = (l15 & 3) ^ ((l15 >> 2) & 3);   // lane-constant swizzle key
    const int ccr = (g ^ key) * 8;                  // ush offset of lane's unit

    #pragma unroll
    for (int kc = 0; kc < 16; ++kc) {
        if (kc < 15) { asm volatile("s_waitcnt vmcnt(3)" ::: "memory"); }
        else         { asm volatile("s_waitcnt vmcnt(0)" ::: "memory"); }
        __builtin_amdgcn_s_barrier();
        asm volatile("" ::: "memory");   // pin ds_reads below the barrier

        const unsigned short* base = smem + (kc % 3) * 6144;
        short8_t af[4], bf[2];
        #pragma unroll
        for (int mt = 0; mt < 4; ++mt)
            af[mt] = *(const short8_t*)(base + (16 * mt + l15) * 32 + ccr);
        #pragma unroll
        for (int ni = 0; ni < 2; ++ni)
            bf[ni] = *(const short8_t*)(base + 2048 + (32 * w + 16 * ni + l15) * 32 + ccr);
        #pragma unroll
        for (int mt = 0; mt < 4; ++mt)
            #pragma unroll
            for (int ni = 0; ni < 2; ++ni)
                acc1[mt][ni] = __builtin_amdgcn_mfma_f32_16x16x32_bf16(
                    af[mt], bf[ni], acc1[mt][ni], 0, 0, 0);

        asm volatile("" ::: "memory");
        if (kc < 14) STAGE1(kc + 2, (kc + 2) % 3);
    }
    #undef STAGE1

    // ---- phase-2 prefetches issued before the h1s barrier (T14) ----
    const unsigned short* W2base = W2f + (size_t)(c * 12 + w * 3) * 8192;
    short8_t bfr[2][4];
    #pragma unroll
    for (int kk = 0; kk < 4; ++kk)
        bfr[0][kk] = *(const short8_t*)(W2base + kk * 512 + l * 8);   // seg0: nt=0

    float w3v[4][4], b2v[4][4];
    #pragma unroll
    for (int nt = 0; nt < 4; ++nt)
        #pragma unroll
        for (int r = 0; r < 4; ++r) {
            w3v[nt][r] = W3[c * H2_ + nt * 16 + g * 4 + r];
            b2v[nt][r] = b2[c * H2_ + nt * 16 + g * 4 + r];
        }
    const float b3v = b3[c];
    const int p = pq >> 2, q = pq & 3;

    __syncthreads();   // all waves' last-iter reads done before h1s overwrite

    // bias + relu -> h1s [64][136] (bank-staggered)
    unsigned short* h1s = smem;
    #pragma unroll
    for (int ni = 0; ni < 2; ++ni) {
        const int i = 32 * w + 16 * ni + l15;
        const float b1v = b1[c * H1_ + i];
        #pragma unroll
        for (int mt = 0; mt < 4; ++mt)
            #pragma unroll
            for (int r = 0; r < 4; ++r) {
                float h = acc1[mt][ni][r] + b1v;
                h = h > 0.f ? h : 0.f;
                h1s[(16 * mt + 4 * g + r) * 136 + i] = f2bf(h);
            }
    }
    __syncthreads();

    // ---------------- Phase 2 (swapped operands) ----------------
    // a2 = h1 B-fragments: row t = 16mt + l15, k = i = 32kk + 8g .. +8
    short8_t a2[4][4];
    #pragma unroll
    for (int mt = 0; mt < 4; ++mt)
        #pragma unroll
        for (int kk = 0; kk < 4; ++kk)
            a2[mt][kk] = *(const short8_t*)&h1s[(16 * mt + l15) * 136 + 32 * kk + 8 * g];

    float s[4] = {0.f, 0.f, 0.f, 0.f};

    // seg = 0..11 : rs_local = seg>>2, nt = seg&3 ; 1-ahead 2-slot prefetch
    #pragma unroll
    for (int seg = 0; seg < 12; ++seg) {
        if (seg < 11) {
            const int ns = seg + 1;
            const unsigned short* nb = W2base + (ns >> 2) * 8192 + ((ns & 3) * 4) * 512;
            #pragma unroll
            for (int kk = 0; kk < 4; ++kk)
                bfr[(seg + 1) & 1][kk] = *(const short8_t*)(nb + kk * 512 + l * 8);
        }
        const int nt = seg & 3;
        #pragma unroll
        for (int mt = 0; mt < 4; ++mt) {
            f32x4 acc2 = (f32x4){0.f, 0.f, 0.f, 0.f};
            #pragma unroll
            for (int kk = 0; kk < 4; ++kk)
                acc2 = __builtin_amdgcn_mfma_f32_16x16x32_bf16(
                    bfr[seg & 1][kk], a2[mt][kk], acc2, 0, 0, 0);
            #pragma unroll
            for (int r = 0; r < 4; ++r)
                s[mt] = fmaf(w3v[nt][r], fmaxf(acc2[r] + b2v[nt][r], 0.f), s[mt]);
        }

        if (nt == 3) {
            const int rs = w * 3 + (seg >> 2);
            const int hrow = p * 3 + (rs >> 2), wcol = q * 4 + (rs & 3);
            #pragma unroll
            for (int mt = 0; mt < 4; ++mt) {
                s[mt] += __shfl_xor(s[mt], 16);
                s[mt] += __shfl_xor(s[mt], 32);
            }
            float v = (g & 1) ? ((g & 2) ? s[3] : s[1]) : ((g & 2) ? s[2] : s[0]);
            v += b3v;
            if (l < T_)
                out[(((size_t)b * T_ + l) * 9 + hrow) * 16 + wcol] =
                    1.f / (1.f + __expf(-v));
            s[0] = s[1] = s[2] = s[3] = 0.f;
        }
    }
}

// ---------------------------------------------------------------------------
// fp32 VALU fallback — used only if ws too small
// ---------------------------------------------------------------------------
__global__ __launch_bounds__(256) void fused_decoder_f32(
    const float* __restrict__ x,   const int* __restrict__ cam,
    const float* __restrict__ W1,  const float* __restrict__ b1,
    const float* __restrict__ W2,  const float* __restrict__ b2,
    const float* __restrict__ W3,  const float* __restrict__ b3,
    float* __restrict__ out)
{
    __shared__ float h1s[T_ * H1_];
    __shared__ float stage[8192];

    const int pq  = blockIdx.x;
    const int b   = blockIdx.y;
    const int p   = pq >> 2, q = pq & 3;
    const int tid = threadIdx.x;
    const int c   = cam[b];

    float* xs  = stage;
    float* w1s = stage + 2048;

    const int ig = tid & 31;
    const int tg = tid >> 5;

    float acc[8][4];
    #pragma unroll
    for (int a = 0; a < 8; ++a)
        #pragma unroll
        for (int j = 0; j < 4; ++j) acc[a][j] = 0.f;

    for (int f0 = 0; f0 < F_; f0 += 32) {
        __syncthreads();
        {
            int lane = tid & 63;
            int sub  = tid >> 6;
            if (lane < T_) {
                #pragma unroll
                for (int m = 0; m < 8; ++m) {
                    int kk = sub * 8 + m;
                    xs[kk * 64 + lane] = x[((size_t)b * F_ + f0 + kk) * T_ + lane];
                }
            }
        }
        for (int e = tid; e < 32 * H1_; e += 256) {
            int kk = e >> 7, i = e & 127;
            w1s[e] = W1[(((size_t)c * F_ + f0 + kk) * H1_ + i) * 12 + pq];
        }
        __syncthreads();
        #pragma unroll 8
        for (int kk = 0; kk < 32; ++kk) {
            float4 bv = *(const float4*)&w1s[kk * 128 + ig * 4];
            float4 a0 = *(const float4*)&xs[kk * 64 + tg * 8];
            float4 a1 = *(const float4*)&xs[kk * 64 + tg * 8 + 4];
            float at[8] = {a0.x, a0.y, a0.z, a0.w, a1.x, a1.y, a1.z, a1.w};
            #pragma unroll
            for (int tt = 0; tt < 8; ++tt) {
                acc[tt][0] = fmaf(at[tt], bv.x, acc[tt][0]);
                acc[tt][1] = fmaf(at[tt], bv.y, acc[tt][1]);
                acc[tt][2] = fmaf(at[tt], bv.z, acc[tt][2]);
                acc[tt][3] = fmaf(at[tt], bv.w, acc[tt][3]);
            }
        }
    }
    {
        float4 b1v = *(const float4*)&b1[c * H1_ + ig * 4];
        #pragma unroll
        for (int tt = 0; tt < 8; ++tt) {
            int t = tg * 8 + tt;
            if (t < T_) {
                float4 hv;
                hv.x = fmaxf(acc[tt][0] + b1v.x, 0.f);
                hv.y = fmaxf(acc[tt][1] + b1v.y, 0.f);
                hv.z = fmaxf(acc[tt][2] + b1v.z, 0.f);
                hv.w = fmaxf(acc[tt][3] + b1v.w, 0.f);
                *(float4*)&h1s[t * H1_ + ig * 4] = hv;
            }
        }
    }

    const int lane = tid & 63;
    const int wv   = tid >> 6;
    const float w3v = W3[c * H2_ + lane];
    const float b2v = b2[c * H2_ + lane];
    const float b3v = b3[c];
    float* w2s = stage;

    for (int rs = 0; rs < 12; ++rs) {
        __syncthreads();
        for (int e = tid; e < H1_ * H2_; e += 256) {
            int i = e >> 6, o = e & 63;
            w2s[e] = W2[(((size_t)c * H1_ + i) * H2_ + o) * 12 + rs];
        }
        __syncthreads();

        float acc2[15];
        #pragma unroll
        for (int j = 0; j < 15; ++j) acc2[j] = 0.f;

        for (int i = 0; i < H1_; i += 4) {
            float wa = w2s[(i + 0) * 64 + lane];
            float wb = w2s[(i + 1) * 64 + lane];
            float wc = w2s[(i + 2) * 64 + lane];
            float wd = w2s[(i + 3) * 64 + lane];
            #pragma unroll
            for (int j = 0; j < 15; ++j) {
                float4 h = *(const float4*)&h1s[(wv * 15 + j) * H1_ + i];
                acc2[j] = fmaf(h.x, wa, acc2[j]);
                acc2[j] = fmaf(h.y, wb, acc2[j]);
                acc2[j] = fmaf(h.z, wc, acc2[j]);
                acc2[j] = fmaf(h.w, wd, acc2[j]);
            }
        }

        const int r = rs >> 2, s = rs & 3;
        const int hrow = p * 3 + r, wcol = q * 4 + s;
        #pragma unroll
        for (int j = 0; j < 15; ++j) {
            float y = w3v * fmaxf(acc2[j] + b2v, 0.f);
            #pragma unroll
            for (int m = 32; m > 0; m >>= 1) y += __shfl_xor(y, m, 64);
            if (lane == j) {
                int t = wv * 15 + j;
                float v = y + b3v;
                out[(((size_t)b * T_ + t) * 9 + hrow) * 16 + wcol] = 1.f / (1.f + __expf(-v));
            }
        }
    }
}

// ---------------------------------------------------------------------------
extern "C" void kernel_launch(void* const* d_in, const int* in_sizes, int n_in,
                              void* d_out, int out_size, void* d_ws, size_t ws_size,
                              hipStream_t stream) {
    const float* x   = (const float*)d_in[0];
    const int*   cam = (const int*)  d_in[1];
    const float* W1  = (const float*)d_in[2];
    const float* b1  = (const float*)d_in[3];
    const float* W2  = (const float*)d_in[4];
    const float* b2  = (const float*)d_in[5];
    const float* W3  = (const float*)d_in[6];
    const float* b3  = (const float*)d_in[7];
    float* outp = (float*)d_out;

    const size_t n_xT  = (size_t)B_ * 32768;            //  4,194,304 (16 kc x 2048)
    const size_t n_w1s = (size_t)C_ * 12 * 65536;       // 11,796,480 (16 kc x 4096)
    const size_t n_w2f = (size_t)C_ * 12 * 16 * 512;    //  1,474,560 (fragment-major)
    const size_t needed = (n_xT + n_w1s + n_w2f) * sizeof(unsigned short)
                        + B_ * sizeof(int);

    if (d_ws != nullptr && ws_size >= needed) {
        unsigned short* xTs = (unsigned short*)d_ws;
        unsigned short* W1p = xTs + n_xT;
        unsigned short* W2p = W1p + n_w1s;
        int* ord = (int*)(W2p + n_w2f);
        prep_all<<<1593, 256, 0, stream>>>(x, W2, W1, cam, xTs, W2p, W1p, ord);
        fused_all<<<dim3(12 * B_), 256, 0, stream>>>(
            xTs, W1p, W2p, cam, ord, b1, b2, W3, b3, outp);
    } else {
        fused_decoder_f32<<<dim3(12, B_), 256, 0, stream>>>(
            x, cam, W1, b1, W2, b2, W3, b3, outp);
    }
}

// Round 18
// 60.570 us; speedup vs baseline: 1.8841x; 1.0044x over previous
//
#include <hip/hip_runtime.h>
#include <hip/hip_bf16.h>
#include <cstdint>

// Problem constants
#define B_  128
#define F_  512
#define T_  60
#define C_  15
#define H1_ 128
#define H2_ 64

typedef short short8_t __attribute__((ext_vector_type(8)));   // 8 bf16 (4 VGPR)
typedef float f32x4    __attribute__((ext_vector_type(4)));   // MFMA acc

static __device__ __forceinline__ unsigned short f2bf(float f) {
    union { float f; uint32_t u; } v; v.f = f;
    uint32_t r = v.u + 0x7FFF + ((v.u >> 16) & 1);   // RNE
    return (unsigned short)(r >> 16);
}

// async 16B global -> LDS DMA (dest = wave-uniform base + lane*16)
static __device__ __forceinline__ void async_cp16(const unsigned short* g, unsigned short* l) {
    __builtin_amdgcn_global_load_lds(
        (const __attribute__((address_space(1))) unsigned int*)g,
        (__attribute__((address_space(3))) unsigned int*)l, 16, 0, 0);
}

// ---------------------------------------------------------------------------
// prep_all: ONE launch for all prep (R16-format images, BK=64 kc-chunks).
//   blocks 0..511   : repack_x  -> xTs (B, 8 kc, swizzled 64x64 image) bf16
//                     unit (kc,t,cc): k = kc*64 + (cc ^ (t&7))*8 .. +8
//   blocks 512..631 : repack_w2 -> W2f fragment-major (16 frag x 512)
//   block  632      : make_order (camera sort)
//   blocks 633..1592: repack_w1 -> W1s (c,pq): 8 kc x swizzled 128x64 image
// ---------------------------------------------------------------------------
__global__ __launch_bounds__(256) void prep_all(
    const float* __restrict__ x, const float* __restrict__ W2,
    const float* __restrict__ W1, const int* __restrict__ cam,
    unsigned short* __restrict__ xTs, unsigned short* __restrict__ W2f,
    unsigned short* __restrict__ W1s, int* __restrict__ ord)
{
    __shared__ float sm[12288];   // 48 KB
    const int blk = blockIdx.x, tid = threadIdx.x;

    if (blk < 512) {
        // ---------------- repack_x ----------------
        float (*xs)[61] = (float(*)[61])sm;          // 128 x 61 floats
        const int f0 = (blk & 3) * 128, b = blk >> 2;
        #pragma unroll
        for (int it = 0; it < 32; ++it) {
            int idx = tid + it * 256;                // 128*64
            int fl = idx >> 6, t = idx & 63;
            if (t < T_) xs[fl][t] = x[((size_t)b * F_ + f0 + fl) * T_ + t];
        }
        __syncthreads();
        #pragma unroll
        for (int it = 0; it < 8; ++it) {
            int idx = tid + it * 256;                // 64 t x 32 f-groups
            int t = idx >> 5, f4 = (idx & 31) * 4;
            ushort4 o;
            o.x = (t < T_) ? f2bf(xs[f4 + 0][t]) : 0;
            o.y = (t < T_) ? f2bf(xs[f4 + 1][t]) : 0;
            o.z = (t < T_) ? f2bf(xs[f4 + 2][t]) : 0;
            o.w = (t < T_) ? f2bf(xs[f4 + 3][t]) : 0;
            const int f = f0 + f4;
            const int kc = f >> 6, within = f & 63;
            const int cc = (within >> 3) ^ (t & 7), half = (within >> 2) & 1;
            *(ushort4*)(xTs + (size_t)b * 32768 + kc * 4096 + t * 64 + cc * 8 + half * 4) = o;
        }
    } else if (blk < 632) {
        // ---------------- repack_w2 (fragment-major) ------------------------
        float (*ls)[384] = (float(*)[384])sm;        // 32 x 384 floats (48KB)
        const int id = blk - 512;                    // 0..119
        const int i0 = (id & 3) * 32, o0 = ((id >> 2) & 1) * 32, c = id >> 3;
        #pragma unroll
        for (int it = 0; it < 12; ++it) {
            int idx = tid + it * 256;
            int il = idx / 96, r = idx - il * 96;
            float4 v = *(const float4*)(W2 + ((size_t)(c * H1_ + i0 + il)) * (H2_ * 12)
                                           + (size_t)o0 * 12 + r * 4);
            *(float4*)&ls[il][r * 4] = v;
        }
        __syncthreads();
        const int o_l = tid >> 3, i_l = (tid & 7) * 4;
        const int o  = o0 + o_l;
        const int nt = o >> 4, l15 = o & 15;
        const int lane = l15 + 16 * ((i_l >> 3) & 3);
        const int kk  = i0 >> 5;
        const int pos = i_l & 7;
        #pragma unroll
        for (int rs = 0; rs < 12; ++rs) {
            ushort4 v;
            v.x = f2bf(ls[i_l + 0][o_l * 12 + rs]);
            v.y = f2bf(ls[i_l + 1][o_l * 12 + rs]);
            v.z = f2bf(ls[i_l + 2][o_l * 12 + rs]);
            v.w = f2bf(ls[i_l + 3][o_l * 12 + rs]);
            *(ushort4*)(W2f + ((size_t)(c * 12 + rs) * 16 + nt * 4 + kk) * 512
                            + lane * 8 + pos) = v;
        }
    } else if (blk == 632) {
        // ---------------- make_order ----------------
        int* cs = (int*)sm;
        if (tid < B_) cs[tid] = cam[tid];
        __syncthreads();
        if (tid < B_) {
            const int cb = cs[tid];
            int rank = 0;
            #pragma unroll 16
            for (int j = 0; j < B_; ++j) {
                int cj = cs[j];
                rank += (cj < cb || (cj == cb && j < tid)) ? 1 : 0;
            }
            ord[rank] = tid;
        }
    } else {
        // ---------------- repack_w1 ----------------
        float (*ls)[384] = (float(*)[384])sm;        // 32 x 384
        const int id = blk - 633;                    // 0..959
        const int f0 = (id & 15) * 32, i0 = ((id >> 4) & 3) * 32, c = id >> 6;
        #pragma unroll
        for (int it = 0; it < 12; ++it) {
            int idx = tid + it * 256;                // 3072 float4
            int fl = idx / 96, r = idx - fl * 96;
            float4 v = *(const float4*)(W1 + ((size_t)(c * F_ + f0 + fl)) * (H1_ * 12)
                                           + (size_t)i0 * 12 + r * 4);
            *(float4*)&ls[fl][r * 4] = v;
        }
        __syncthreads();
        const int i_l = tid >> 3, f_l = (tid & 7) * 4;
        const int i = i0 + i_l, f = f0 + f_l;
        const int kc = f >> 6, within = f & 63;
        const int cc = (within >> 3) ^ (i & 7), half = (within >> 2) & 1;
        #pragma unroll
        for (int pq = 0; pq < 12; ++pq) {
            ushort4 o;
            o.x = f2bf(ls[f_l + 0][i_l * 12 + pq]);
            o.y = f2bf(ls[f_l + 1][i_l * 12 + pq]);
            o.z = f2bf(ls[f_l + 2][i_l * 12 + pq]);
            o.w = f2bf(ls[f_l + 3][i_l * 12 + pq]);
            *(ushort4*)(W1s + (size_t)(c * 12 + pq) * 65536
                            + kc * 8192 + i * 64 + cc * 8 + half * 4) = o;
        }
    }
}

// ---------------------------------------------------------------------------
// Fused decoder v18 = R16's proven fused_all verbatim (BK=64, 2-buffer LDS
// staging, counted vmcnt(6), 44.4 us measured) — R17's BK=32 regressed
// (2.75M bank conflicts). Phase2: swapped mfma(W2frag, h1frag) + cheap
// g-reduction; W2 prefetch + w3/b2 loads before the h1s barrier (T14).
// ---------------------------------------------------------------------------
__global__ __launch_bounds__(256) void fused_all(
    const unsigned short* __restrict__ xTs, const unsigned short* __restrict__ W1s,
    const unsigned short* __restrict__ W2f, const int* __restrict__ cam,
    const int* __restrict__ ord,
    const float* __restrict__ b1, const float* __restrict__ b2,
    const float* __restrict__ W3, const float* __restrict__ b3,
    float* __restrict__ out)
{
    __shared__ __align__(16) unsigned short smem[24576];   // 48 KB

    const int idx = blockIdx.x;
    const int swz = (idx & 7) * 192 + (idx >> 3);   // bijective XCD swizzle
    const int bpos = swz / 12, pq = swz - bpos * 12;
    const int b = ord[bpos];

    const int tid = threadIdx.x;
    const int w = tid >> 6, l = tid & 63;
    const int l15 = l & 15, g = l >> 4;
    const int c = cam[b];

    // ---------------- Phase 1: h1(64x128) = xT(64x512) * W1^T ----------------
    const unsigned short* xchunk = xTs + (size_t)b * 32768;             // 8 x 4096
    const unsigned short* wchunk = W1s + (size_t)(c * 12 + pq) * 65536; // 8 x 8192

    #define STAGE1(kc, buf)                                                       \
        {                                                                         \
            _Pragma("unroll")                                                     \
            for (int k = 0; k < 2; ++k)                                           \
                async_cp16(xchunk + (kc) * 4096 + (w * 2 + k) * 512 + l * 8,      \
                           smem + (buf) * 12288 + (w * 2 + k) * 512 + l * 8);     \
            _Pragma("unroll")                                                     \
            for (int k = 0; k < 4; ++k)                                           \
                async_cp16(wchunk + (kc) * 8192 + (w * 4 + k) * 512 + l * 8,      \
                           smem + (buf) * 12288 + 4096 + (w * 4 + k) * 512 + l * 8); \
        }

    f32x4 acc1[4][2];
    #pragma unroll
    for (int mt = 0; mt < 4; ++mt) {
        acc1[mt][0] = (f32x4){0.f, 0.f, 0.f, 0.f};
        acc1[mt][1] = (f32x4){0.f, 0.f, 0.f, 0.f};
    }

    STAGE1(0, 0);
    STAGE1(1, 1);

    const int sxor = (l15 & 7);
    #pragma unroll
    for (int kc = 0; kc < 8; ++kc) {
        if (kc < 7) { asm volatile("s_waitcnt vmcnt(6)" ::: "memory"); }
        else        { asm volatile("s_waitcnt vmcnt(0)" ::: "memory"); }
        __builtin_amdgcn_s_barrier();
        asm volatile("" ::: "memory");

        const int base = (kc & 1) * 12288;
        #pragma unroll
        for (int kk2 = 0; kk2 < 2; ++kk2) {
            const int cc = (kk2 * 4 + g) ^ sxor;
            short8_t af[4], bf[2];
            #pragma unroll
            for (int mt = 0; mt < 4; ++mt)
                af[mt] = *(const short8_t*)(smem + base + (16 * mt + l15) * 64 + cc * 8);
            #pragma unroll
            for (int ni = 0; ni < 2; ++ni)
                bf[ni] = *(const short8_t*)(smem + base + 4096
                                            + (32 * w + 16 * ni + l15) * 64 + cc * 8);
            #pragma unroll
            for (int mt = 0; mt < 4; ++mt)
                #pragma unroll
                for (int ni = 0; ni < 2; ++ni)
                    acc1[mt][ni] = __builtin_amdgcn_mfma_f32_16x16x32_bf16(
                        af[mt], bf[ni], acc1[mt][ni], 0, 0, 0);
        }

        asm volatile("" ::: "memory");
        __builtin_amdgcn_s_barrier();
        if (kc < 6) STAGE1(kc + 2, kc & 1);
    }
    #undef STAGE1

    // ---- phase-2 prefetches issued before the h1s barrier (T14) ----
    const unsigned short* W2base = W2f + (size_t)(c * 12 + w * 3) * 8192;
    short8_t bfr[2][4];
    #pragma unroll
    for (int kk = 0; kk < 4; ++kk)
        bfr[0][kk] = *(const short8_t*)(W2base + kk * 512 + l * 8);   // seg0: nt=0

    float w3v[4][4], b2v[4][4];
    #pragma unroll
    for (int nt = 0; nt < 4; ++nt)
        #pragma unroll
        for (int r = 0; r < 4; ++r) {
            w3v[nt][r] = W3[c * H2_ + nt * 16 + g * 4 + r];
            b2v[nt][r] = b2[c * H2_ + nt * 16 + g * 4 + r];
        }
    const float b3v = b3[c];
    const int p = pq >> 2, q = pq & 3;

    // bias + relu -> h1s [64][136] (bank-staggered)
    unsigned short* h1s = smem;
    #pragma unroll
    for (int ni = 0; ni < 2; ++ni) {
        const int i = 32 * w + 16 * ni + l15;
        const float b1v = b1[c * H1_ + i];
        #pragma unroll
        for (int mt = 0; mt < 4; ++mt)
            #pragma unroll
            for (int r = 0; r < 4; ++r) {
                float h = acc1[mt][ni][r] + b1v;
                h = h > 0.f ? h : 0.f;
                h1s[(16 * mt + 4 * g + r) * 136 + i] = f2bf(h);
            }
    }
    __syncthreads();

    // ---------------- Phase 2 (swapped operands) ----------------
    // a2 = h1 B-fragments: row t = 16mt + l15, k = i = 32kk + 8g .. +8
    short8_t a2[4][4];
    #pragma unroll
    for (int mt = 0; mt < 4; ++mt)
        #pragma unroll
        for (int kk = 0; kk < 4; ++kk)
            a2[mt][kk] = *(const short8_t*)&h1s[(16 * mt + l15) * 136 + 32 * kk + 8 * g];

    float s[4] = {0.f, 0.f, 0.f, 0.f};

    // seg = 0..11 : rs_local = seg>>2, nt = seg&3 ; 1-ahead 2-slot prefetch
    #pragma unroll
    for (int seg = 0; seg < 12; ++seg) {
        if (seg < 11) {
            const int ns = seg + 1;
            const unsigned short* nb = W2base + (ns >> 2) * 8192 + ((ns & 3) * 4) * 512;
            #pragma unroll
            for (int kk = 0; kk < 4; ++kk)
                bfr[(seg + 1) & 1][kk] = *(const short8_t*)(nb + kk * 512 + l * 8);
        }
        const int nt = seg & 3;
        #pragma unroll
        for (int mt = 0; mt < 4; ++mt) {
            f32x4 acc2 = (f32x4){0.f, 0.f, 0.f, 0.f};
            #pragma unroll
            for (int kk = 0; kk < 4; ++kk)
                acc2 = __builtin_amdgcn_mfma_f32_16x16x32_bf16(
                    bfr[seg & 1][kk], a2[mt][kk], acc2, 0, 0, 0);
            #pragma unroll
            for (int r = 0; r < 4; ++r)
                s[mt] = fmaf(w3v[nt][r], fmaxf(acc2[r] + b2v[nt][r], 0.f), s[mt]);
        }

        if (nt == 3) {
            const int rs = w * 3 + (seg >> 2);
            const int hrow = p * 3 + (rs >> 2), wcol = q * 4 + (rs & 3);
            #pragma unroll
            for (int mt = 0; mt < 4; ++mt) {
                s[mt] += __shfl_xor(s[mt], 16);
                s[mt] += __shfl_xor(s[mt], 32);
            }
            float v = (g & 1) ? ((g & 2) ? s[3] : s[1]) : ((g & 2) ? s[2] : s[0]);
            v += b3v;
            if (l < T_)
                out[(((size_t)b * T_ + l) * 9 + hrow) * 16 + wcol] =
                    1.f / (1.f + __expf(-v));
            s[0] = s[1] = s[2] = s[3] = 0.f;
        }
    }
}

// ---------------------------------------------------------------------------
// fp32 VALU fallback — used only if ws too small
// ---------------------------------------------------------------------------
__global__ __launch_bounds__(256) void fused_decoder_f32(
    const float* __restrict__ x,   const int* __restrict__ cam,
    const float* __restrict__ W1,  const float* __restrict__ b1,
    const float* __restrict__ W2,  const float* __restrict__ b2,
    const float* __restrict__ W3,  const float* __restrict__ b3,
    float* __restrict__ out)
{
    __shared__ float h1s[T_ * H1_];
    __shared__ float stage[8192];

    const int pq  = blockIdx.x;
    const int b   = blockIdx.y;
    const int p   = pq >> 2, q = pq & 3;
    const int tid = threadIdx.x;
    const int c   = cam[b];

    float* xs  = stage;
    float* w1s = stage + 2048;

    const int ig = tid & 31;
    const int tg = tid >> 5;

    float acc[8][4];
    #pragma unroll
    for (int a = 0; a < 8; ++a)
        #pragma unroll
        for (int j = 0; j < 4; ++j) acc[a][j] = 0.f;

    for (int f0 = 0; f0 < F_; f0 += 32) {
        __syncthreads();
        {
            int lane = tid & 63;
            int sub  = tid >> 6;
            if (lane < T_) {
                #pragma unroll
                for (int m = 0; m < 8; ++m) {
                    int kk = sub * 8 + m;
                    xs[kk * 64 + lane] = x[((size_t)b * F_ + f0 + kk) * T_ + lane];
                }
            }
        }
        for (int e = tid; e < 32 * H1_; e += 256) {
            int kk = e >> 7, i = e & 127;
            w1s[e] = W1[(((size_t)c * F_ + f0 + kk) * H1_ + i) * 12 + pq];
        }
        __syncthreads();
        #pragma unroll 8
        for (int kk = 0; kk < 32; ++kk) {
            float4 bv = *(const float4*)&w1s[kk * 128 + ig * 4];
            float4 a0 = *(const float4*)&xs[kk * 64 + tg * 8];
            float4 a1 = *(const float4*)&xs[kk * 64 + tg * 8 + 4];
            float at[8] = {a0.x, a0.y, a0.z, a0.w, a1.x, a1.y, a1.z, a1.w};
            #pragma unroll
            for (int tt = 0; tt < 8; ++tt) {
                acc[tt][0] = fmaf(at[tt], bv.x, acc[tt][0]);
                acc[tt][1] = fmaf(at[tt], bv.y, acc[tt][1]);
                acc[tt][2] = fmaf(at[tt], bv.z, acc[tt][2]);
                acc[tt][3] = fmaf(at[tt], bv.w, acc[tt][3]);
            }
        }
    }
    {
        float4 b1v = *(const float4*)&b1[c * H1_ + ig * 4];
        #pragma unroll
        for (int tt = 0; tt < 8; ++tt) {
            int t = tg * 8 + tt;
            if (t < T_) {
                float4 hv;
                hv.x = fmaxf(acc[tt][0] + b1v.x, 0.f);
                hv.y = fmaxf(acc[tt][1] + b1v.y, 0.f);
                hv.z = fmaxf(acc[tt][2] + b1v.z, 0.f);
                hv.w = fmaxf(acc[tt][3] + b1v.w, 0.f);
                *(float4*)&h1s[t * H1_ + ig * 4] = hv;
            }
        }
    }

    const int lane = tid & 63;
    const int wv   = tid >> 6;
    const float w3v = W3[c * H2_ + lane];
    const float b2v = b2[c * H2_ + lane];
    const float b3v = b3[c];
    float* w2s = stage;

    for (int rs = 0; rs < 12; ++rs) {
        __syncthreads();
        for (int e = tid; e < H1_ * H2_; e += 256) {
            int i = e >> 6, o = e & 63;
            w2s[e] = W2[(((size_t)c * H1_ + i) * H2_ + o) * 12 + rs];
        }
        __syncthreads();

        float acc2[15];
        #pragma unroll
        for (int j = 0; j < 15; ++j) acc2[j] = 0.f;

        for (int i = 0; i < H1_; i += 4) {
            float wa = w2s[(i + 0) * 64 + lane];
            float wb = w2s[(i + 1) * 64 + lane];
            float wc = w2s[(i + 2) * 64 + lane];
            float wd = w2s[(i + 3) * 64 + lane];
            #pragma unroll
            for (int j = 0; j < 15; ++j) {
                float4 h = *(const float4*)&h1s[(wv * 15 + j) * H1_ + i];
                acc2[j] = fmaf(h.x, wa, acc2[j]);
                acc2[j] = fmaf(h.y, wb, acc2[j]);
                acc2[j] = fmaf(h.z, wc, acc2[j]);
                acc2[j] = fmaf(h.w, wd, acc2[j]);
            }
        }

        const int r = rs >> 2, s = rs & 3;
        const int hrow = p * 3 + r, wcol = q * 4 + s;
        #pragma unroll
        for (int j = 0; j < 15; ++j) {
            float y = w3v * fmaxf(acc2[j] + b2v, 0.f);
            #pragma unroll
            for (int m = 32; m > 0; m >>= 1) y += __shfl_xor(y, m, 64);
            if (lane == j) {
                int t = wv * 15 + j;
                float v = y + b3v;
                out[(((size_t)b * T_ + t) * 9 + hrow) * 16 + wcol] = 1.f / (1.f + __expf(-v));
            }
        }
    }
}

// ---------------------------------------------------------------------------
extern "C" void kernel_launch(void* const* d_in, const int* in_sizes, int n_in,
                              void* d_out, int out_size, void* d_ws, size_t ws_size,
                              hipStream_t stream) {
    const float* x   = (const float*)d_in[0];
    const int*   cam = (const int*)  d_in[1];
    const float* W1  = (const float*)d_in[2];
    const float* b1  = (const float*)d_in[3];
    const float* W2  = (const float*)d_in[4];
    const float* b2  = (const float*)d_in[5];
    const float* W3  = (const float*)d_in[6];
    const float* b3  = (const float*)d_in[7];
    float* outp = (float*)d_out;

    const size_t n_xT  = (size_t)B_ * 32768;            //  4,194,304 (8 kc x 4096)
    const size_t n_w1s = (size_t)C_ * 12 * 65536;       // 11,796,480 (8 kc x 8192)
    const size_t n_w2f = (size_t)C_ * 12 * 16 * 512;    //  1,474,560 (fragment-major)
    const size_t needed = (n_xT + n_w1s + n_w2f) * sizeof(unsigned short)
                        + B_ * sizeof(int);

    if (d_ws != nullptr && ws_size >= needed) {
        unsigned short* xTs = (unsigned short*)d_ws;
        unsigned short* W1p = xTs + n_xT;
        unsigned short* W2p = W1p + n_w1s;
        int* ord = (int*)(W2p + n_w2f);
        prep_all<<<1593, 256, 0, stream>>>(x, W2, W1, cam, xTs, W2p, W1p, ord);
        fused_all<<<dim3(12 * B_), 256, 0, stream>>>(
            xTs, W1p, W2p, cam, ord, b1, b2, W3, b3, outp);
    } else {
        fused_decoder_f32<<<dim3(12, B_), 256, 0, stream>>>(
            x, cam, W1, b1, W2, b2, W3, b3, outp);
    }
}